// Round 4
// baseline (626.055 us; speedup 1.0000x reference)
//
#include <hip/hip_runtime.h>
#include <hip/hip_bf16.h>
#include <cstdint>

#define DI __device__ __forceinline__

typedef short bf16x8 __attribute__((ext_vector_type(8)));
typedef float f32x4 __attribute__((ext_vector_type(4)));
typedef unsigned short u16;
typedef unsigned short u16x4 __attribute__((ext_vector_type(4)));
typedef unsigned short u16x8 __attribute__((ext_vector_type(8)));

static constexpr int NV = 10, NE = 90, TT = 64;
static constexpr int R1 = 20480;   // 32*10*64 node rows
static constexpr int R2 = 184320;  // 32*90*64 edge rows

DI float bf2f(u16 u) { union { unsigned int i; float f; } x; x.i = ((unsigned int)u) << 16; return x.f; }
DI u16 f2bf(float f) { unsigned int u = __float_as_uint(f); return (u16)((u + 0x7FFF + ((u >> 16) & 1)) >> 16); }
DI float elu(float v) { return v > 0.f ? v : __expf(v) - 1.f; }

#define GLL(srcp, dstp) __builtin_amdgcn_global_load_lds( \
    (const __attribute__((address_space(1))) unsigned int*)(srcp), \
    (__attribute__((address_space(3))) unsigned int*)(dstp), 16, 0, 0)

// ---- combined weight transposes: [256,256] f32 -> [256,256] bf16 (n-major) --
__global__ __launch_bounds__(256) void transpose_all(
    const float* __restrict__ s0, u16* __restrict__ d0,
    const float* __restrict__ s1, u16* __restrict__ d1,
    const float* __restrict__ s2, u16* __restrict__ d2,
    const float* __restrict__ s3, u16* __restrict__ d3,
    const float* __restrict__ s4, u16* __restrict__ d4) {
    const float* s; u16* d;
    switch (blockIdx.y) {
        case 0: s = s0; d = d0; break;
        case 1: s = s1; d = d1; break;
        case 2: s = s2; d = d2; break;
        case 3: s = s3; d = d3; break;
        default: s = s4; d = d4; break;
    }
    int idx = blockIdx.x * 256 + threadIdx.x;
    int k = idx >> 8, n = idx & 255;
    d[(size_t)n * 256 + k] = f2bf(s[idx]);
}

__global__ void zero_stats(float* p, int n) {
    int i = blockIdx.x * 256 + threadIdx.x;
    if (i < n) p[i] = 0.f;
}

__global__ void conv_wo2(const float* __restrict__ src, u16* __restrict__ dst) {
    dst[threadIdx.x] = f2bf(src[threadIdx.x]);
}

// fold BN1 affine scale into w2a (transposed), shift into bias
__global__ __launch_bounds__(256) void fold_w2a(const float* __restrict__ w2a,
                                                const float* __restrict__ scsh1,
                                                u16* __restrict__ w2aT) {
    int k = blockIdx.x, n = threadIdx.x;
    w2aT[(size_t)n * 512 + k] = f2bf(scsh1[k & 255] * w2a[k * 256 + n]);
}
__global__ __launch_bounds__(256) void fold_b2a(const float* __restrict__ w2a,
                                                const float* __restrict__ scsh1,
                                                const float* __restrict__ b2a,
                                                float* __restrict__ b2aF) {
    int n = threadIdx.x;
    float s = b2a[n];
    for (int k = 0; k < 512; ++k) s += scsh1[256 + (k & 255)] * w2a[k * 256 + n];
    b2aF[n] = s;
}

__global__ void stats_final(const float* __restrict__ sums, const float* __restrict__ g,
                            const float* __restrict__ be, float invR, float* __restrict__ scsh) {
    int c = threadIdx.x;
    float mu = sums[c] * invR;
    float var = sums[256 + c] * invR - mu * mu;
    float rs = rsqrtf(var + 1e-5f);
    float sc = g[c] * rs;
    scsh[c] = sc;
    scsh[256 + c] = be[c] - mu * sc;
}

// -------------------- mlp1 fc1: K=4, VALU (round-1 verified) -----------------
__global__ __launch_bounds__(256) void mlp1_fc1(const float* __restrict__ x,
                                                const float* __restrict__ w1a,
                                                const float* __restrict__ b1a,
                                                u16* __restrict__ ha) {
    int tid = threadIdx.x;
    int row = blockIdx.x * 8 + (tid >> 5);
    int ch8 = (tid & 31) * 8;
    int b = row / (NV * TT);
    int v = (row >> 6) % NV;
    int t = row & 63;
    const float* xp = x + ((size_t)(b * TT + t) * NV + v) * 4;
    float x0 = xp[0], x1 = xp[1], x2 = xp[2], x3 = xp[3];
    u16x8 pack;
#pragma unroll
    for (int e = 0; e < 8; ++e) {
        int c = ch8 + e;
        float acc = b1a[c] + x0 * w1a[c] + x1 * w1a[256 + c] + x2 * w1a[512 + c] + x3 * w1a[768 + c];
        pack[e] = f2bf(elu(acc));
    }
    *(u16x8*)(ha + (size_t)row * 256 + ch8) = pack;
}

// ============================================================================
// 128x128 bf16 MFMA GEMM, BK=32, 4 waves, single-buffered (round-1 engine).
// CONFLICT-FREE BY CONSTRUCTION: staging lanes are chunk-major (lane = c*16+rr)
// so the LDS layout is [G-group][chunk c][row rr] with G = 16 rows. The GLL
// dest stays linear (base + lane*16B, rule #21) and the fragment ds_read_b128
// at byte offset G*1024 + lane*16 is fully linear (m134 ideal, 0 conflicts).
// Global side per GLL: lanes {rr, rr+16, rr+32, rr+48} read row rr's 4 chunks
// = contiguous 64B -> 16 x 64B transactions (same as round 1).
// Operand swap: acc[i][j] = mfma(bv[j], av[i], .) -> lane holds
//   col m = m0+wm*64+i*16+lr, rows n4..n4+3, n4 = n0+wn*64+j*16+g*4
// STG: 0 direct | 1 node2edge gather | 3 affine+relu reg-staged ds_write
// ACT: 1 elu | 2 relu.  STATS: fused per-channel sum/sumsq atomics.
// ============================================================================
template <int STG, int ACT, bool STATS>
__global__ __launch_bounds__(256) void mm(
    const u16* __restrict__ A, int K,
    const u16* __restrict__ Wt, const float* __restrict__ bias,
    const float* __restrict__ aux,
    u16* __restrict__ outB, float* __restrict__ stats)
{
    __shared__ u16 As[128 * 32];   // 8 KB, layout [G][c][rr] (512 u16 per G)
    __shared__ u16 Bs[128 * 32];   // 8 KB

    const int tid = threadIdx.x;
    const int wid = tid >> 6, lane = tid & 63;
    const int g = lane >> 4, lr = lane & 15;
    const int bm = blockIdx.x >> 1, bn = blockIdx.x & 1;
    const int m0 = bm * 128, n0 = bn * 128;
    const int wm = wid >> 1, wn = wid & 1;
    const int rr = lane & 15;      // staged row within G-group
    const int cc = lane >> 4;      // staged chunk (8 u16)
    const int G0 = wid * 2, G1 = wid * 2 + 1;

    // per-thread global source bases (named scalars; no arrays)
    size_t a0 = 0, a1 = 0, sb0 = 0, sb1 = 0, rb0 = 0, rb1 = 0;
    if constexpr (STG == 1) {
        {
            int m = m0 + G0 * 16 + rr;
            int t = m & 63, be = m >> 6, e = be % NE, b = be / NE;
            int s = e / 9, kk = e - s * 9, r = kk + (kk >= s ? 1 : 0);
            sb0 = ((size_t)((b * NV + s) * TT + t)) * 256 + cc * 8;
            rb0 = ((size_t)((b * NV + r) * TT + t)) * 256 + cc * 8;
        }
        {
            int m = m0 + G1 * 16 + rr;
            int t = m & 63, be = m >> 6, e = be % NE, b = be / NE;
            int s = e / 9, kk = e - s * 9, r = kk + (kk >= s ? 1 : 0);
            sb1 = ((size_t)((b * NV + s) * TT + t)) * 256 + cc * 8;
            rb1 = ((size_t)((b * NV + r) * TT + t)) * 256 + cc * 8;
        }
    } else if constexpr (STG == 0) {
        a0 = (size_t)(m0 + G0 * 16 + rr) * K + cc * 8;
        a1 = (size_t)(m0 + G1 * 16 + rr) * K + cc * 8;
    }
    const size_t b0 = (size_t)(n0 + G0 * 16 + rr) * K + cc * 8;
    const size_t b1 = (size_t)(n0 + G1 * 16 + rr) * K + cc * 8;

    f32x4 acc[4][4];
#pragma unroll
    for (int i = 0; i < 4; ++i)
#pragma unroll
        for (int j = 0; j < 4; ++j) acc[i][j] = (f32x4)0.f;

    for (int k0 = 0; k0 < K; k0 += 32) {
        // ---- stage A ----
        if constexpr (STG == 0) {
            GLL(A + a0 + k0, As + G0 * 512);
            GLL(A + a1 + k0, As + G1 * 512);
        } else if constexpr (STG == 1) {
            // BK=32 step never crosses the 256 concat boundary
            GLL(A + (k0 < 256 ? sb0 : rb0) + (k0 & 255), As + G0 * 512);
            GLL(A + (k0 < 256 ? sb1 : rb1) + (k0 & 255), As + G1 * 512);
        } else {  // STG == 3: affine(aux)+relu, register-staged ds_write
#pragma unroll
            for (int q = 0; q < 2; ++q) {
                int G = wid * 2 + q;
                int row = m0 + G * 16 + rr;
                u16x8 vin = *(const u16x8*)(A + (size_t)row * 256 + k0 + cc * 8);
                u16x8 pk;
#pragma unroll
                for (int e = 0; e < 8; ++e) {
                    int ch = k0 + cc * 8 + e;
                    float f = bf2f(vin[e]) * aux[ch] + aux[256 + ch];
                    pk[e] = f2bf(f > 0.f ? f : 0.f);
                }
                *(u16x8*)&As[G * 512 + lane * 8] = pk;
            }
        }
        // ---- stage B (weights) ----
        GLL(Wt + b0 + k0, Bs + G0 * 512);
        GLL(Wt + b1 + k0, Bs + G1 * 512);
        __syncthreads();
        // ---- fragments (linear b128 reads, conflict-free) + MFMA ----
        bf16x8 av[4], bv[4];
#pragma unroll
        for (int i = 0; i < 4; ++i)
            av[i] = *(const bf16x8*)&As[(wm * 4 + i) * 512 + g * 128 + lr * 8];
#pragma unroll
        for (int j = 0; j < 4; ++j)
            bv[j] = *(const bf16x8*)&Bs[(wn * 4 + j) * 512 + g * 128 + lr * 8];
#pragma unroll
        for (int i = 0; i < 4; ++i)
#pragma unroll
            for (int j = 0; j < 4; ++j)
                acc[i][j] = __builtin_amdgcn_mfma_f32_16x16x32_bf16(bv[j], av[i], acc[i][j], 0, 0, 0);
        __syncthreads();
    }

    // ---- epilogue: bias + act (+stats) + packed store ----
    float sv[4][4], qv[4][4];
    if constexpr (STATS) {
#pragma unroll
        for (int j = 0; j < 4; ++j)
#pragma unroll
            for (int r = 0; r < 4; ++r) { sv[j][r] = 0.f; qv[j][r] = 0.f; }
    }
#pragma unroll
    for (int j = 0; j < 4; ++j) {
        int n4 = n0 + wn * 64 + j * 16 + g * 4;
        f32x4 bq = *(const f32x4*)(bias + n4);
#pragma unroll
        for (int i = 0; i < 4; ++i) {
            int m = m0 + wm * 64 + i * 16 + lr;
            u16x4 pk;
#pragma unroll
            for (int r = 0; r < 4; ++r) {
                float v = acc[i][j][r] + bq[r];
                v = (ACT == 1) ? elu(v) : (v > 0.f ? v : 0.f);
                if constexpr (STATS) { sv[j][r] += v; qv[j][r] += v * v; }
                pk[r] = f2bf(v);
            }
            *(u16x4*)(outB + (size_t)m * 256 + n4) = pk;
        }
    }
    if constexpr (STATS) {
#pragma unroll
        for (int j = 0; j < 4; ++j)
#pragma unroll
            for (int r = 0; r < 4; ++r) {
                float s = sv[j][r], q_ = qv[j][r];
                s += __shfl_xor(s, 1);  q_ += __shfl_xor(q_, 1);
                s += __shfl_xor(s, 2);  q_ += __shfl_xor(q_, 2);
                s += __shfl_xor(s, 4);  q_ += __shfl_xor(q_, 4);
                s += __shfl_xor(s, 8);  q_ += __shfl_xor(q_, 8);
                if (lr == 0) {
                    int n = n0 + wn * 64 + j * 16 + g * 4 + r;
                    atomicAdd(&stats[n], s);
                    atomicAdd(&stats[256 + n], q_);
                }
            }
    }
}

// -------------------- edge2node: incidence sum + BN2 affine (verified) -------
__global__ __launch_bounds__(256) void edge2node(const u16* __restrict__ h2,
                                                 const float* __restrict__ scsh2,
                                                 u16* __restrict__ n1) {
    int tid = threadIdx.x;
    int row = blockIdx.x * 8 + (tid >> 5);
    int ch8 = (tid & 31) * 8;
    int t = row & 63;
    int bv = row >> 6;
    int v = bv % NV;
    int b = bv / NV;
    float acc[8] = {0, 0, 0, 0, 0, 0, 0, 0};
#pragma unroll
    for (int i = 0; i < 9; ++i) {
        int s = i + (i >= v ? 1 : 0);
        int e = s * 9 + (v < s ? v : v - 1);
        u16x8 vv = *(const u16x8*)(h2 + ((size_t)((b * NE + e) * TT + t)) * 256 + ch8);
#pragma unroll
        for (int k = 0; k < 8; ++k) acc[k] += bf2f(vv[k]);
    }
    const float inv9 = 1.f / 9.f;
    u16x8 o;
#pragma unroll
    for (int k = 0; k < 8; ++k) {
        int c = ch8 + k;
        o[k] = f2bf(scsh2[c] * (acc[k] * inv9) + scsh2[256 + c]);
    }
    *(u16x8*)(n1 + (size_t)row * 256 + ch8) = o;
}

// -------------------- final head: dot(a2_row, wo2) + bo2 (verified) ----------
__global__ __launch_bounds__(256) void head2(const u16* __restrict__ a2,
                                             const u16* __restrict__ wo2t,
                                             const float* __restrict__ bo2,
                                             float* __restrict__ out) {
    int tid = threadIdx.x;
    int row = blockIdx.x * 8 + (tid >> 5);
    int l32 = tid & 31;
    int ch8 = l32 * 8;
    u16x8 a = *(const u16x8*)(a2 + (size_t)row * 256 + ch8);
    u16x8 w = *(const u16x8*)(wo2t + ch8);
    float p = 0.f;
#pragma unroll
    for (int k = 0; k < 8; ++k) p += bf2f(a[k]) * bf2f(w[k]);
#pragma unroll
    for (int off = 16; off > 0; off >>= 1) p += __shfl_down(p, off, 32);
    if (l32 == 0) {
        int b = row / (NV * TT);
        int v = (row >> 6) % NV;
        int t = row & 63;
        out[(size_t)(b * TT + t) * NV + v] = p + bo2[0];
    }
}

extern "C" void kernel_launch(void* const* d_in, const int* in_sizes, int n_in,
                              void* d_out, int out_size, void* d_ws, size_t ws_size,
                              hipStream_t stream) {
    const float* x   = (const float*)d_in[0];
    const float* w1a = (const float*)d_in[1];
    const float* b1a = (const float*)d_in[2];
    const float* w1b = (const float*)d_in[3];
    const float* b1b = (const float*)d_in[4];
    const float* g1  = (const float*)d_in[5];
    const float* be1 = (const float*)d_in[6];
    const float* w2a = (const float*)d_in[7];
    const float* b2a = (const float*)d_in[8];
    const float* w2b = (const float*)d_in[9];
    const float* b2b = (const float*)d_in[10];
    const float* g2  = (const float*)d_in[11];
    const float* be2 = (const float*)d_in[12];
    const float* w3a = (const float*)d_in[13];
    const float* b3a = (const float*)d_in[14];
    const float* w3b = (const float*)d_in[15];
    const float* b3b = (const float*)d_in[16];
    const float* g3  = (const float*)d_in[17];
    const float* be3 = (const float*)d_in[18];
    const float* wo1 = (const float*)d_in[19];
    const float* bo1 = (const float*)d_in[20];
    const float* wo2 = (const float*)d_in[21];
    const float* bo2 = (const float*)d_in[22];
    float* out = (float*)d_out;

    char* ws = (char*)d_ws;
    size_t off = 0;
    auto alloc = [&](size_t bytes) {
        void* p = ws + off;
        off = (off + bytes + 255) & ~(size_t)255;
        return p;
    };
    u16* w1bT = (u16*)alloc(256 * 256 * 2);
    u16* w2aT = (u16*)alloc(256 * 512 * 2);
    u16* w2bT = (u16*)alloc(256 * 256 * 2);
    u16* w3aT = (u16*)alloc(256 * 256 * 2);
    u16* w3bT = (u16*)alloc(256 * 256 * 2);
    u16* wo1T = (u16*)alloc(256 * 256 * 2);
    u16* wo2T = (u16*)alloc(256 * 2);
    float* sums  = (float*)alloc(3 * 512 * 4);
    float* scsh1 = (float*)alloc(512 * 4);
    float* scsh2 = (float*)alloc(512 * 4);
    float* scsh3 = (float*)alloc(512 * 4);
    float* b2aF  = (float*)alloc(256 * 4);
    u16* S0 = (u16*)alloc((size_t)R1 * 256 * 2);
    u16* S1 = (u16*)alloc((size_t)R1 * 256 * 2);
    u16* S2 = (u16*)alloc((size_t)R1 * 256 * 2);
    u16* BIG1 = (u16*)alloc((size_t)R2 * 256 * 2);
    u16* BIG2 = (u16*)alloc((size_t)R2 * 256 * 2);

    dim3 tgrid(256, 5);
    transpose_all<<<tgrid, 256, 0, stream>>>(w1b, w1bT, w2b, w2bT, w3a, w3aT,
                                             w3b, w3bT, wo1, wo1T);
    zero_stats<<<6, 256, 0, stream>>>(sums, 3 * 512);
    conv_wo2<<<1, 256, 0, stream>>>(wo2, wo2T);

    // mlp1: fc1 (VALU) + fc2 GEMM with fused stats
    mlp1_fc1<<<R1 / 8, 256, 0, stream>>>(x, w1a, b1a, S0);
    mm<0, 1, true><<<(R1 / 128) * 2, 256, 0, stream>>>(S0, 256, w1bT, b1b, nullptr, S1, sums);
    stats_final<<<1, 256, 0, stream>>>(sums, g1, be1, 1.f / R1, scsh1);
    fold_w2a<<<512, 256, 0, stream>>>(w2a, scsh1, w2aT);
    fold_b2a<<<1, 256, 0, stream>>>(w2a, scsh1, b2a, b2aF);

    // mlp2: gather fc1 (BN1 folded into weights), fc2 with fused stats
    mm<1, 1, false><<<(R2 / 128) * 2, 256, 0, stream>>>(S1, 512, w2aT, b2aF, nullptr, BIG1, nullptr);
    mm<0, 1, true><<<(R2 / 128) * 2, 256, 0, stream>>>(BIG1, 256, w2bT, b2b, nullptr, BIG2, sums + 512);
    stats_final<<<1, 256, 0, stream>>>(sums + 512, g2, be2, 1.f / R2, scsh2);

    edge2node<<<R1 / 8, 256, 0, stream>>>(BIG2, scsh2, S0);

    // mlp3: two GEMMs, stats fused into fc2
    mm<0, 1, false><<<(R1 / 128) * 2, 256, 0, stream>>>(S0, 256, w3aT, b3a, nullptr, S1, nullptr);
    mm<0, 1, true><<<(R1 / 128) * 2, 256, 0, stream>>>(S1, 256, w3bT, b3b, nullptr, S2, sums + 1024);
    stats_final<<<1, 256, 0, stream>>>(sums + 1024, g3, be3, 1.f / R1, scsh3);

    // head: affine3+relu staged into wo1 GEMM, relu stored; then dot wo2
    mm<3, 2, false><<<(R1 / 128) * 2, 256, 0, stream>>>(S2, 256, wo1T, bo1, scsh3, S1, nullptr);
    head2<<<R1 / 8, 256, 0, stream>>>(S1, wo2T, bo2, out);
}

// Round 5
// 293.682 us; speedup vs baseline: 2.1317x; 2.1317x over previous
//
#include <hip/hip_runtime.h>
#include <hip/hip_bf16.h>
#include <cstdint>

#define DI __device__ __forceinline__

typedef short bf16x8 __attribute__((ext_vector_type(8)));
typedef float f32x4 __attribute__((ext_vector_type(4)));
typedef unsigned short u16;
typedef unsigned short u16x8 __attribute__((ext_vector_type(8)));

static constexpr int NV = 10, NE = 90, TT = 64;
static constexpr int R1 = 20480;   // 32*10*64 node rows
static constexpr int R2 = 184320;  // 32*90*64 edge rows

DI float bf2f(u16 u) { union { unsigned int i; float f; } x; x.i = ((unsigned int)u) << 16; return x.f; }
DI u16 f2bf(float f) { unsigned int u = __float_as_uint(f); return (u16)((u + 0x7FFF + ((u >> 16) & 1)) >> 16); }
DI float elu(float v) { return v > 0.f ? v : __expf(v) - 1.f; }

#define GLL(srcp, dstp) __builtin_amdgcn_global_load_lds( \
    (const __attribute__((address_space(1))) unsigned int*)(srcp), \
    (__attribute__((address_space(3))) unsigned int*)(dstp), 16, 0, 0)

// ---- combined weight transposes: [256,256] f32 -> [256,256] bf16 (n-major) --
__global__ __launch_bounds__(256) void transpose_all(
    const float* __restrict__ s0, u16* __restrict__ d0,
    const float* __restrict__ s1, u16* __restrict__ d1,
    const float* __restrict__ s2, u16* __restrict__ d2,
    const float* __restrict__ s3, u16* __restrict__ d3,
    const float* __restrict__ s4, u16* __restrict__ d4) {
    const float* s; u16* d;
    switch (blockIdx.y) {
        case 0: s = s0; d = d0; break;
        case 1: s = s1; d = d1; break;
        case 2: s = s2; d = d2; break;
        case 3: s = s3; d = d3; break;
        default: s = s4; d = d4; break;
    }
    int idx = blockIdx.x * 256 + threadIdx.x;
    int k = idx >> 8, n = idx & 255;
    d[(size_t)n * 256 + k] = f2bf(s[idx]);
}

__global__ void zero_stats(float* p, int n) {
    int i = blockIdx.x * 256 + threadIdx.x;
    if (i < n) p[i] = 0.f;
}

__global__ void conv_wo2(const float* __restrict__ src, u16* __restrict__ dst) {
    dst[threadIdx.x] = f2bf(src[threadIdx.x]);
}

// fold BN1 affine scale into w2a (transposed), shift into bias
__global__ __launch_bounds__(256) void fold_w2a(const float* __restrict__ w2a,
                                                const float* __restrict__ scsh1,
                                                u16* __restrict__ w2aT) {
    int k = blockIdx.x, n = threadIdx.x;
    w2aT[(size_t)n * 512 + k] = f2bf(scsh1[k & 255] * w2a[k * 256 + n]);
}
__global__ __launch_bounds__(256) void fold_b2a(const float* __restrict__ w2a,
                                                const float* __restrict__ scsh1,
                                                const float* __restrict__ b2a,
                                                float* __restrict__ b2aF) {
    int n = threadIdx.x;
    float s = b2a[n];
    for (int k = 0; k < 512; ++k) s += scsh1[256 + (k & 255)] * w2a[k * 256 + n];
    b2aF[n] = s;
}

__global__ void stats_final(const float* __restrict__ sums, const float* __restrict__ g,
                            const float* __restrict__ be, float invR, float* __restrict__ scsh) {
    int c = threadIdx.x;
    float mu = sums[c] * invR;
    float var = sums[256 + c] * invR - mu * mu;
    float rs = rsqrtf(var + 1e-5f);
    float sc = g[c] * rs;
    scsh[c] = sc;
    scsh[256 + c] = be[c] - mu * sc;
}

// -------------------- mlp1 fc1: K=4, VALU (round-1 verified) -----------------
__global__ __launch_bounds__(256) void mlp1_fc1(const float* __restrict__ x,
                                                const float* __restrict__ w1a,
                                                const float* __restrict__ b1a,
                                                u16* __restrict__ ha) {
    int tid = threadIdx.x;
    int row = blockIdx.x * 8 + (tid >> 5);
    int ch8 = (tid & 31) * 8;
    int b = row / (NV * TT);
    int v = (row >> 6) % NV;
    int t = row & 63;
    const float* xp = x + ((size_t)(b * TT + t) * NV + v) * 4;
    float x0 = xp[0], x1 = xp[1], x2 = xp[2], x3 = xp[3];
    u16x8 pack;
#pragma unroll
    for (int e = 0; e < 8; ++e) {
        int c = ch8 + e;
        float acc = b1a[c] + x0 * w1a[c] + x1 * w1a[256 + c] + x2 * w1a[512 + c] + x3 * w1a[768 + c];
        pack[e] = f2bf(elu(acc));
    }
    *(u16x8*)(ha + (size_t)row * 256 + ch8) = pack;
}

// ============================================================================
// ROUND-1 VERIFIED ENGINE (88 us, MfmaUtil 23%) + two contained deltas:
//   (a) double-buffered LDS: prefetch next K-tile's GLL before current tile's
//       compute; ONE __syncthreads per K-step (was two).
//   (b) optional fused per-channel stats in the epilogue (col depends only on
//       lr, so shfl_xor over lane bits 4..5 reduces; one atomic per col/wave).
// All lane mappings (staging srow=tid>>2, [row][32] LDS, fragment reads,
// mfma(a,b) order, scalar-store epilogue) are byte-identical to round 1.
// ============================================================================
template <bool GATHER, int ACT, bool STATS>   // ACT: 1 elu, 2 relu
__global__ __launch_bounds__(256) void gemm_kernel(const u16* __restrict__ A,
                                                   const u16* __restrict__ Wt,
                                                   const float* __restrict__ bias,
                                                   u16* __restrict__ out,
                                                   int K,
                                                   float* __restrict__ stats) {
    __shared__ u16 As[2][128 * 32];
    __shared__ u16 Bs[2][128 * 32];
    const int tid = threadIdx.x;
    const int lane = tid & 63, wid = tid >> 6;
    const int bm = blockIdx.x >> 1, bn = blockIdx.x & 1;
    const int m0 = bm * 128, n0 = bn * 128;
    const int wm = wid >> 1, wn = wid & 1;

    const int srow = tid >> 2;           // 0..63 staging row
    const int scol8 = (tid & 3) * 8;     // k-chunk within BK

    size_t abase[2], bbase[2], sb[2], rb[2];
    if constexpr (GATHER) {
#pragma unroll
        for (int p = 0; p < 2; ++p) {
            int m = m0 + srow + p * 64;        // edge row
            int t = m & 63;
            int be = m >> 6;
            int e = be % NE;
            int b = be / NE;
            int s = e / 9;
            int kk = e - s * 9;
            int r = kk + (kk >= s ? 1 : 0);
            sb[p] = ((size_t)((b * NV + s) * TT + t)) * 256;
            rb[p] = ((size_t)((b * NV + r) * TT + t)) * 256;
        }
    } else {
#pragma unroll
        for (int p = 0; p < 2; ++p) abase[p] = (size_t)(m0 + srow + p * 64) * K;
    }
#pragma unroll
    for (int p = 0; p < 2; ++p) bbase[p] = (size_t)(n0 + srow + p * 64) * K;

    f32x4 acc[4][4];
#pragma unroll
    for (int i = 0; i < 4; ++i)
#pragma unroll
        for (int j = 0; j < 4; ++j) acc[i][j] = (f32x4)0.f;

    const int lrow = lane & 15;
    const int lk8 = (lane >> 4) * 8;

    auto stage = [&](int bf, int k0) {
#pragma unroll
        for (int p = 0; p < 2; ++p) {
            const u16* asrc;
            if constexpr (GATHER) {
                int f = k0 + scol8;
                asrc = A + (f < 256 ? sb[p] + f : rb[p] + (f - 256));
            } else {
                asrc = A + abase[p] + k0 + scol8;
            }
            GLL(asrc, &As[bf][(p * 256 + wid * 64) * 8]);
            GLL(Wt + bbase[p] + k0 + scol8, &Bs[bf][(p * 256 + wid * 64) * 8]);
        }
    };

    stage(0, 0);
    __syncthreads();
    int buf = 0;
    for (int k0 = 0; k0 < K; k0 += 32) {
        if (k0 + 32 < K) stage(buf ^ 1, k0 + 32);   // prefetch overlaps compute
        bf16x8 a[4], b[4];
#pragma unroll
        for (int i = 0; i < 4; ++i)
            a[i] = *(const bf16x8*)&As[buf][(wm * 64 + i * 16 + lrow) * 32 + lk8];
#pragma unroll
        for (int j = 0; j < 4; ++j)
            b[j] = *(const bf16x8*)&Bs[buf][(wn * 64 + j * 16 + lrow) * 32 + lk8];
#pragma unroll
        for (int i = 0; i < 4; ++i)
#pragma unroll
            for (int j = 0; j < 4; ++j)
                acc[i][j] = __builtin_amdgcn_mfma_f32_16x16x32_bf16(a[i], b[j], acc[i][j], 0, 0, 0);
        __syncthreads();   // readers done with buf AND prefetch (vmcnt drain) landed
        buf ^= 1;
    }

    // ---- epilogue: round-1 scalar stores + optional fused stats ----
    float bv[4], sv[4], qv[4];
#pragma unroll
    for (int j = 0; j < 4; ++j) {
        bv[j] = bias[n0 + wn * 64 + j * 16 + lrow];
        if constexpr (STATS) { sv[j] = 0.f; qv[j] = 0.f; }
    }
#pragma unroll
    for (int i = 0; i < 4; ++i) {
#pragma unroll
        for (int j = 0; j < 4; ++j) {
            int col = n0 + wn * 64 + j * 16 + lrow;
#pragma unroll
            for (int r = 0; r < 4; ++r) {
                int row = m0 + wm * 64 + i * 16 + (lane >> 4) * 4 + r;
                float v = acc[i][j][r] + bv[j];
                v = (ACT == 1) ? elu(v) : (v > 0.f ? v : 0.f);
                if constexpr (STATS) { sv[j] += v; qv[j] += v * v; }
                out[(size_t)row * 256 + col] = f2bf(v);
            }
        }
    }
    if constexpr (STATS) {
        // col depends only on lrow: reduce over lane bits 4,5 (the g groups)
#pragma unroll
        for (int j = 0; j < 4; ++j) {
            float s = sv[j], q_ = qv[j];
            s += __shfl_xor(s, 16); q_ += __shfl_xor(q_, 16);
            s += __shfl_xor(s, 32); q_ += __shfl_xor(q_, 32);
            if ((lane >> 4) == 0) {
                int col = n0 + wn * 64 + j * 16 + lrow;
                atomicAdd(&stats[col], s);
                atomicAdd(&stats[256 + col], q_);
            }
        }
    }
}

// -------------------- elementwise affine + relu (BN3, round-1 verified) ------
__global__ __launch_bounds__(256) void norm_affine_relu(const u16* __restrict__ in,
                                                        const float* __restrict__ scsh,
                                                        u16* __restrict__ out, int n8) {
    int i = blockIdx.x * 256 + threadIdx.x;
    if (i >= n8) return;
    size_t base = (size_t)i * 8;
    int ch8 = (int)(base & 255);
    u16x8 v = *(const u16x8*)(in + base);
    u16x8 o;
#pragma unroll
    for (int e = 0; e < 8; ++e) {
        float f = bf2f(v[e]);
        f = scsh[ch8 + e] * f + scsh[256 + ch8 + e];
        o[e] = f2bf(f > 0.f ? f : 0.f);
    }
    *(u16x8*)(out + base) = o;
}

// -------------------- edge2node: incidence sum + BN2 affine (verified) -------
__global__ __launch_bounds__(256) void edge2node(const u16* __restrict__ h2,
                                                 const float* __restrict__ scsh2,
                                                 u16* __restrict__ n1) {
    int tid = threadIdx.x;
    int row = blockIdx.x * 8 + (tid >> 5);
    int ch8 = (tid & 31) * 8;
    int t = row & 63;
    int bv = row >> 6;
    int v = bv % NV;
    int b = bv / NV;
    float acc[8] = {0, 0, 0, 0, 0, 0, 0, 0};
#pragma unroll
    for (int i = 0; i < 9; ++i) {
        int s = i + (i >= v ? 1 : 0);
        int e = s * 9 + (v < s ? v : v - 1);
        u16x8 vv = *(const u16x8*)(h2 + ((size_t)((b * NE + e) * TT + t)) * 256 + ch8);
#pragma unroll
        for (int k = 0; k < 8; ++k) acc[k] += bf2f(vv[k]);
    }
    const float inv9 = 1.f / 9.f;
    u16x8 o;
#pragma unroll
    for (int k = 0; k < 8; ++k) {
        int c = ch8 + k;
        o[k] = f2bf(scsh2[c] * (acc[k] * inv9) + scsh2[256 + c]);
    }
    *(u16x8*)(n1 + (size_t)row * 256 + ch8) = o;
}

// -------------------- final head: dot(a2_row, wo2) + bo2 (verified) ----------
__global__ __launch_bounds__(256) void head2(const u16* __restrict__ a2,
                                             const u16* __restrict__ wo2t,
                                             const float* __restrict__ bo2,
                                             float* __restrict__ out) {
    int tid = threadIdx.x;
    int row = blockIdx.x * 8 + (tid >> 5);
    int l32 = tid & 31;
    int ch8 = l32 * 8;
    u16x8 a = *(const u16x8*)(a2 + (size_t)row * 256 + ch8);
    u16x8 w = *(const u16x8*)(wo2t + ch8);
    float p = 0.f;
#pragma unroll
    for (int k = 0; k < 8; ++k) p += bf2f(a[k]) * bf2f(w[k]);
#pragma unroll
    for (int off = 16; off > 0; off >>= 1) p += __shfl_down(p, off, 32);
    if (l32 == 0) {
        int b = row / (NV * TT);
        int v = (row >> 6) % NV;
        int t = row & 63;
        out[(size_t)(b * TT + t) * NV + v] = p + bo2[0];
    }
}

extern "C" void kernel_launch(void* const* d_in, const int* in_sizes, int n_in,
                              void* d_out, int out_size, void* d_ws, size_t ws_size,
                              hipStream_t stream) {
    const float* x   = (const float*)d_in[0];
    const float* w1a = (const float*)d_in[1];
    const float* b1a = (const float*)d_in[2];
    const float* w1b = (const float*)d_in[3];
    const float* b1b = (const float*)d_in[4];
    const float* g1  = (const float*)d_in[5];
    const float* be1 = (const float*)d_in[6];
    const float* w2a = (const float*)d_in[7];
    const float* b2a = (const float*)d_in[8];
    const float* w2b = (const float*)d_in[9];
    const float* b2b = (const float*)d_in[10];
    const float* g2  = (const float*)d_in[11];
    const float* be2 = (const float*)d_in[12];
    const float* w3a = (const float*)d_in[13];
    const float* b3a = (const float*)d_in[14];
    const float* w3b = (const float*)d_in[15];
    const float* b3b = (const float*)d_in[16];
    const float* g3  = (const float*)d_in[17];
    const float* be3 = (const float*)d_in[18];
    const float* wo1 = (const float*)d_in[19];
    const float* bo1 = (const float*)d_in[20];
    const float* wo2 = (const float*)d_in[21];
    const float* bo2 = (const float*)d_in[22];
    float* out = (float*)d_out;

    char* ws = (char*)d_ws;
    size_t off = 0;
    auto alloc = [&](size_t bytes) {
        void* p = ws + off;
        off = (off + bytes + 255) & ~(size_t)255;
        return p;
    };
    u16* w1bT = (u16*)alloc(256 * 256 * 2);
    u16* w2aT = (u16*)alloc(256 * 512 * 2);
    u16* w2bT = (u16*)alloc(256 * 256 * 2);
    u16* w3aT = (u16*)alloc(256 * 256 * 2);
    u16* w3bT = (u16*)alloc(256 * 256 * 2);
    u16* wo1T = (u16*)alloc(256 * 256 * 2);
    u16* wo2T = (u16*)alloc(256 * 2);
    float* sums  = (float*)alloc(3 * 512 * 4);
    float* scsh1 = (float*)alloc(512 * 4);
    float* scsh2 = (float*)alloc(512 * 4);
    float* scsh3 = (float*)alloc(512 * 4);
    float* b2aF  = (float*)alloc(256 * 4);
    u16* S0 = (u16*)alloc((size_t)R1 * 256 * 2);
    u16* S1 = (u16*)alloc((size_t)R1 * 256 * 2);
    u16* S2 = (u16*)alloc((size_t)R1 * 256 * 2);
    u16* BIG1 = (u16*)alloc((size_t)R2 * 256 * 2);
    u16* BIG2 = (u16*)alloc((size_t)R2 * 256 * 2);

    dim3 tgrid(256, 5);
    transpose_all<<<tgrid, 256, 0, stream>>>(w1b, w1bT, w2b, w2bT, w3a, w3aT,
                                             w3b, w3bT, wo1, wo1T);
    zero_stats<<<6, 256, 0, stream>>>(sums, 3 * 512);
    conv_wo2<<<1, 256, 0, stream>>>(wo2, wo2T);

    // mlp1: fc1 (VALU) + fc2 GEMM with fused stats
    mlp1_fc1<<<R1 / 8, 256, 0, stream>>>(x, w1a, b1a, S0);
    gemm_kernel<false, 1, true><<<(R1 / 128) * 2, 256, 0, stream>>>(S0, w1bT, b1b, S1, 256, sums);
    stats_final<<<1, 256, 0, stream>>>(sums, g1, be1, 1.f / R1, scsh1);
    fold_w2a<<<512, 256, 0, stream>>>(w2a, scsh1, w2aT);
    fold_b2a<<<1, 256, 0, stream>>>(w2a, scsh1, b2a, b2aF);

    // mlp2: gather fc1 (BN1 folded into weights), fc2 with fused stats
    gemm_kernel<true, 1, false><<<(R2 / 128) * 2, 256, 0, stream>>>(S1, w2aT, b2aF, BIG1, 512, nullptr);
    gemm_kernel<false, 1, true><<<(R2 / 128) * 2, 256, 0, stream>>>(BIG1, w2bT, b2b, BIG2, 256, sums + 512);
    stats_final<<<1, 256, 0, stream>>>(sums + 512, g2, be2, 1.f / R2, scsh2);

    // edge2node (BN2 affine folded in)
    edge2node<<<R1 / 8, 256, 0, stream>>>(BIG2, scsh2, S0);

    // mlp3: two GEMMs, stats fused into fc2
    gemm_kernel<false, 1, false><<<(R1 / 128) * 2, 256, 0, stream>>>(S0, w3aT, b3a, S1, 256, nullptr);
    gemm_kernel<false, 1, true><<<(R1 / 128) * 2, 256, 0, stream>>>(S1, w3bT, b3b, S2, 256, sums + 1024);
    stats_final<<<1, 256, 0, stream>>>(sums + 1024, g3, be3, 1.f / R1, scsh3);

    // head: BN3 affine+relu, wo1 GEMM (relu), dot wo2
    norm_affine_relu<<<(R1 * 32 + 255) / 256, 256, 0, stream>>>(S2, scsh3, S0, R1 * 32);
    gemm_kernel<false, 2, false><<<(R1 / 128) * 2, 256, 0, stream>>>(S0, wo1T, bo1, S1, 256, nullptr);
    head2<<<R1 / 8, 256, 0, stream>>>(S1, wo2T, bo2, out);
}

// Round 6
// 281.792 us; speedup vs baseline: 2.2217x; 1.0422x over previous
//
#include <hip/hip_runtime.h>
#include <hip/hip_bf16.h>
#include <cstdint>

#define DI __device__ __forceinline__

typedef short bf16x8 __attribute__((ext_vector_type(8)));
typedef float f32x4 __attribute__((ext_vector_type(4)));
typedef unsigned short u16;
typedef unsigned short u16x8 __attribute__((ext_vector_type(8)));

static constexpr int NV = 10, NE = 90, TT = 64;
static constexpr int R1 = 20480;   // 32*10*64 node rows
static constexpr int R2 = 184320;  // 32*90*64 edge rows

DI float bf2f(u16 u) { union { unsigned int i; float f; } x; x.i = ((unsigned int)u) << 16; return x.f; }
DI u16 f2bf(float f) { unsigned int u = __float_as_uint(f); return (u16)((u + 0x7FFF + ((u >> 16) & 1)) >> 16); }
DI float elu(float v) { return v > 0.f ? v : __expf(v) - 1.f; }

#define GLL(srcp, dstp) __builtin_amdgcn_global_load_lds( \
    (const __attribute__((address_space(1))) unsigned int*)(srcp), \
    (__attribute__((address_space(3))) unsigned int*)(dstp), 16, 0, 0)

// ---- combined weight transposes: [256,256] f32 -> [256,256] bf16 (n-major) --
__global__ __launch_bounds__(256) void transpose_all(
    const float* __restrict__ s0, u16* __restrict__ d0,
    const float* __restrict__ s1, u16* __restrict__ d1,
    const float* __restrict__ s2, u16* __restrict__ d2,
    const float* __restrict__ s3, u16* __restrict__ d3,
    const float* __restrict__ s4, u16* __restrict__ d4) {
    const float* s; u16* d;
    switch (blockIdx.y) {
        case 0: s = s0; d = d0; break;
        case 1: s = s1; d = d1; break;
        case 2: s = s2; d = d2; break;
        case 3: s = s3; d = d3; break;
        default: s = s4; d = d4; break;
    }
    int idx = blockIdx.x * 256 + threadIdx.x;
    int k = idx >> 8, n = idx & 255;
    d[(size_t)n * 256 + k] = f2bf(s[idx]);
}

__global__ void zero_stats(float* p, int n) {
    int i = blockIdx.x * 256 + threadIdx.x;
    if (i < n) p[i] = 0.f;
}

__global__ void conv_wo2(const float* __restrict__ src, u16* __restrict__ dst) {
    dst[threadIdx.x] = f2bf(src[threadIdx.x]);
}

// fold BN1 affine scale into w2a (transposed), shift into bias
__global__ __launch_bounds__(256) void fold_w2a(const float* __restrict__ w2a,
                                                const float* __restrict__ scsh1,
                                                u16* __restrict__ w2aT) {
    int k = blockIdx.x, n = threadIdx.x;
    w2aT[(size_t)n * 512 + k] = f2bf(scsh1[k & 255] * w2a[k * 256 + n]);
}
__global__ __launch_bounds__(256) void fold_b2a(const float* __restrict__ w2a,
                                                const float* __restrict__ scsh1,
                                                const float* __restrict__ b2a,
                                                float* __restrict__ b2aF) {
    int n = threadIdx.x;
    float s = b2a[n];
    for (int k = 0; k < 512; ++k) s += scsh1[256 + (k & 255)] * w2a[k * 256 + n];
    b2aF[n] = s;
}

__global__ void stats_final(const float* __restrict__ sums, const float* __restrict__ g,
                            const float* __restrict__ be, float invR, float* __restrict__ scsh) {
    int c = threadIdx.x;
    float mu = sums[c] * invR;
    float var = sums[256 + c] * invR - mu * mu;
    float rs = rsqrtf(var + 1e-5f);
    float sc = g[c] * rs;
    scsh[c] = sc;
    scsh[256 + c] = be[c] - mu * sc;
}

// -------------------- mlp1 fc1: K=4, VALU (round-1 verified) -----------------
__global__ __launch_bounds__(256) void mlp1_fc1(const float* __restrict__ x,
                                                const float* __restrict__ w1a,
                                                const float* __restrict__ b1a,
                                                u16* __restrict__ ha) {
    int tid = threadIdx.x;
    int row = blockIdx.x * 8 + (tid >> 5);
    int ch8 = (tid & 31) * 8;
    int b = row / (NV * TT);
    int v = (row >> 6) % NV;
    int t = row & 63;
    const float* xp = x + ((size_t)(b * TT + t) * NV + v) * 4;
    float x0 = xp[0], x1 = xp[1], x2 = xp[2], x3 = xp[3];
    u16x8 pack;
#pragma unroll
    for (int e = 0; e < 8; ++e) {
        int c = ch8 + e;
        float acc = b1a[c] + x0 * w1a[c] + x1 * w1a[256 + c] + x2 * w1a[512 + c] + x3 * w1a[768 + c];
        pack[e] = f2bf(elu(acc));
    }
    *(u16x8*)(ha + (size_t)row * 256 + ch8) = pack;
}

// ============================================================================
// ROUND-5 VERIFIED ENGINE (dbuf, 1 barrier/K-step, fused stats) + XCD swizzle.
// SWZ=0 (pair): bn-pair sharing an A-tile co-locates on one XCD's L2.
// SWZ=1 (gather/batch): all 90 blocks of one batch co-locate on one XCD so the
//   batch's 327 KB node slice stays L2-resident across the 9x gather reuse.
// Both mappings are bijections of [0, gridDim.x) assuming wg->XCD = bid%8.
// ============================================================================
template <bool GATHER, int ACT, bool STATS, int SWZ>   // ACT: 1 elu, 2 relu
__global__ __launch_bounds__(256) void gemm_kernel(const u16* __restrict__ A,
                                                   const u16* __restrict__ Wt,
                                                   const float* __restrict__ bias,
                                                   u16* __restrict__ out,
                                                   int K,
                                                   float* __restrict__ stats) {
    __shared__ u16 As[2][128 * 32];
    __shared__ u16 Bs[2][128 * 32];
    const int tid = threadIdx.x;
    const int lane = tid & 63, wid = tid >> 6;

    int bm, bn;
    {
        int bid = blockIdx.x;
        int xcd = bid & 7, slot = bid >> 3;
        if constexpr (SWZ == 1) {
            // 2880 blocks: 32 batches x 45 bm x 2 bn; batch -> fixed XCD
            int batch = xcd + 8 * (slot / 90);
            int j = slot % 90;
            bn = j & 1;
            bm = batch * 45 + (j >> 1);
        } else {
            bn = slot & 1;
            bm = xcd + 8 * (slot >> 1);
        }
    }
    const int m0 = bm * 128, n0 = bn * 128;
    const int wm = wid >> 1, wn = wid & 1;

    const int srow = tid >> 2;           // 0..63 staging row
    const int scol8 = (tid & 3) * 8;     // k-chunk within BK

    size_t abase[2], bbase[2], sb[2], rb[2];
    if constexpr (GATHER) {
#pragma unroll
        for (int p = 0; p < 2; ++p) {
            int m = m0 + srow + p * 64;        // edge row
            int t = m & 63;
            int be = m >> 6;
            int e = be % NE;
            int b = be / NE;
            int s = e / 9;
            int kk = e - s * 9;
            int r = kk + (kk >= s ? 1 : 0);
            sb[p] = ((size_t)((b * NV + s) * TT + t)) * 256;
            rb[p] = ((size_t)((b * NV + r) * TT + t)) * 256;
        }
    } else {
#pragma unroll
        for (int p = 0; p < 2; ++p) abase[p] = (size_t)(m0 + srow + p * 64) * K;
    }
#pragma unroll
    for (int p = 0; p < 2; ++p) bbase[p] = (size_t)(n0 + srow + p * 64) * K;

    f32x4 acc[4][4];
#pragma unroll
    for (int i = 0; i < 4; ++i)
#pragma unroll
        for (int j = 0; j < 4; ++j) acc[i][j] = (f32x4)0.f;

    const int lrow = lane & 15;
    const int lk8 = (lane >> 4) * 8;

    auto stage = [&](int bf, int k0) {
#pragma unroll
        for (int p = 0; p < 2; ++p) {
            const u16* asrc;
            if constexpr (GATHER) {
                int f = k0 + scol8;
                asrc = A + (f < 256 ? sb[p] + f : rb[p] + (f - 256));
            } else {
                asrc = A + abase[p] + k0 + scol8;
            }
            GLL(asrc, &As[bf][(p * 256 + wid * 64) * 8]);
            GLL(Wt + bbase[p] + k0 + scol8, &Bs[bf][(p * 256 + wid * 64) * 8]);
        }
    };

    stage(0, 0);
    __syncthreads();
    int buf = 0;
    for (int k0 = 0; k0 < K; k0 += 32) {
        if (k0 + 32 < K) stage(buf ^ 1, k0 + 32);   // prefetch overlaps compute
        bf16x8 a[4], b[4];
#pragma unroll
        for (int i = 0; i < 4; ++i)
            a[i] = *(const bf16x8*)&As[buf][(wm * 64 + i * 16 + lrow) * 32 + lk8];
#pragma unroll
        for (int j = 0; j < 4; ++j)
            b[j] = *(const bf16x8*)&Bs[buf][(wn * 64 + j * 16 + lrow) * 32 + lk8];
#pragma unroll
        for (int i = 0; i < 4; ++i)
#pragma unroll
            for (int j = 0; j < 4; ++j)
                acc[i][j] = __builtin_amdgcn_mfma_f32_16x16x32_bf16(a[i], b[j], acc[i][j], 0, 0, 0);
        __syncthreads();   // readers done with buf AND prefetch landed
        buf ^= 1;
    }

    // ---- epilogue: bias + act (+fused stats) + store ----
    float bv[4], sv[4], qv[4];
#pragma unroll
    for (int j = 0; j < 4; ++j) {
        bv[j] = bias[n0 + wn * 64 + j * 16 + lrow];
        if constexpr (STATS) { sv[j] = 0.f; qv[j] = 0.f; }
    }
#pragma unroll
    for (int i = 0; i < 4; ++i) {
#pragma unroll
        for (int j = 0; j < 4; ++j) {
            int col = n0 + wn * 64 + j * 16 + lrow;
#pragma unroll
            for (int r = 0; r < 4; ++r) {
                int row = m0 + wm * 64 + i * 16 + (lane >> 4) * 4 + r;
                float v = acc[i][j][r] + bv[j];
                v = (ACT == 1) ? elu(v) : (v > 0.f ? v : 0.f);
                if constexpr (STATS) { sv[j] += v; qv[j] += v * v; }
                out[(size_t)row * 256 + col] = f2bf(v);
            }
        }
    }
    if constexpr (STATS) {
        // col depends only on lrow: reduce over lane bits 4,5
#pragma unroll
        for (int j = 0; j < 4; ++j) {
            float s = sv[j], q_ = qv[j];
            s += __shfl_xor(s, 16); q_ += __shfl_xor(q_, 16);
            s += __shfl_xor(s, 32); q_ += __shfl_xor(q_, 32);
            if ((lane >> 4) == 0) {
                int col = n0 + wn * 64 + j * 16 + lrow;
                atomicAdd(&stats[col], s);
                atomicAdd(&stats[256 + col], q_);
            }
        }
    }
}

// -------------------- elementwise affine + relu (BN3) ------------------------
__global__ __launch_bounds__(256) void norm_affine_relu(const u16* __restrict__ in,
                                                        const float* __restrict__ scsh,
                                                        u16* __restrict__ out, int n8) {
    int i = blockIdx.x * 256 + threadIdx.x;
    if (i >= n8) return;
    size_t base = (size_t)i * 8;
    int ch8 = (int)(base & 255);
    u16x8 v = *(const u16x8*)(in + base);
    u16x8 o;
#pragma unroll
    for (int e = 0; e < 8; ++e) {
        float f = bf2f(v[e]);
        f = scsh[ch8 + e] * f + scsh[256 + ch8 + e];
        o[e] = f2bf(f > 0.f ? f : 0.f);
    }
    *(u16x8*)(out + base) = o;
}

// -------------------- edge2node: incidence sum + BN2 affine (verified) -------
__global__ __launch_bounds__(256) void edge2node(const u16* __restrict__ h2,
                                                 const float* __restrict__ scsh2,
                                                 u16* __restrict__ n1) {
    int tid = threadIdx.x;
    int row = blockIdx.x * 8 + (tid >> 5);
    int ch8 = (tid & 31) * 8;
    int t = row & 63;
    int bv = row >> 6;
    int v = bv % NV;
    int b = bv / NV;
    float acc[8] = {0, 0, 0, 0, 0, 0, 0, 0};
#pragma unroll
    for (int i = 0; i < 9; ++i) {
        int s = i + (i >= v ? 1 : 0);
        int e = s * 9 + (v < s ? v : v - 1);
        u16x8 vv = *(const u16x8*)(h2 + ((size_t)((b * NE + e) * TT + t)) * 256 + ch8);
#pragma unroll
        for (int k = 0; k < 8; ++k) acc[k] += bf2f(vv[k]);
    }
    const float inv9 = 1.f / 9.f;
    u16x8 o;
#pragma unroll
    for (int k = 0; k < 8; ++k) {
        int c = ch8 + k;
        o[k] = f2bf(scsh2[c] * (acc[k] * inv9) + scsh2[256 + c]);
    }
    *(u16x8*)(n1 + (size_t)row * 256 + ch8) = o;
}

// -------------------- final head: dot(a2_row, wo2) + bo2 (verified) ----------
__global__ __launch_bounds__(256) void head2(const u16* __restrict__ a2,
                                             const u16* __restrict__ wo2t,
                                             const float* __restrict__ bo2,
                                             float* __restrict__ out) {
    int tid = threadIdx.x;
    int row = blockIdx.x * 8 + (tid >> 5);
    int l32 = tid & 31;
    int ch8 = l32 * 8;
    u16x8 a = *(const u16x8*)(a2 + (size_t)row * 256 + ch8);
    u16x8 w = *(const u16x8*)(wo2t + ch8);
    float p = 0.f;
#pragma unroll
    for (int k = 0; k < 8; ++k) p += bf2f(a[k]) * bf2f(w[k]);
#pragma unroll
    for (int off = 16; off > 0; off >>= 1) p += __shfl_down(p, off, 32);
    if (l32 == 0) {
        int b = row / (NV * TT);
        int v = (row >> 6) % NV;
        int t = row & 63;
        out[(size_t)(b * TT + t) * NV + v] = p + bo2[0];
    }
}

extern "C" void kernel_launch(void* const* d_in, const int* in_sizes, int n_in,
                              void* d_out, int out_size, void* d_ws, size_t ws_size,
                              hipStream_t stream) {
    const float* x   = (const float*)d_in[0];
    const float* w1a = (const float*)d_in[1];
    const float* b1a = (const float*)d_in[2];
    const float* w1b = (const float*)d_in[3];
    const float* b1b = (const float*)d_in[4];
    const float* g1  = (const float*)d_in[5];
    const float* be1 = (const float*)d_in[6];
    const float* w2a = (const float*)d_in[7];
    const float* b2a = (const float*)d_in[8];
    const float* w2b = (const float*)d_in[9];
    const float* b2b = (const float*)d_in[10];
    const float* g2  = (const float*)d_in[11];
    const float* be2 = (const float*)d_in[12];
    const float* w3a = (const float*)d_in[13];
    const float* b3a = (const float*)d_in[14];
    const float* w3b = (const float*)d_in[15];
    const float* b3b = (const float*)d_in[16];
    const float* g3  = (const float*)d_in[17];
    const float* be3 = (const float*)d_in[18];
    const float* wo1 = (const float*)d_in[19];
    const float* bo1 = (const float*)d_in[20];
    const float* wo2 = (const float*)d_in[21];
    const float* bo2 = (const float*)d_in[22];
    float* out = (float*)d_out;

    char* ws = (char*)d_ws;
    size_t off = 0;
    auto alloc = [&](size_t bytes) {
        void* p = ws + off;
        off = (off + bytes + 255) & ~(size_t)255;
        return p;
    };
    u16* w1bT = (u16*)alloc(256 * 256 * 2);
    u16* w2aT = (u16*)alloc(256 * 512 * 2);
    u16* w2bT = (u16*)alloc(256 * 256 * 2);
    u16* w3aT = (u16*)alloc(256 * 256 * 2);
    u16* w3bT = (u16*)alloc(256 * 256 * 2);
    u16* wo1T = (u16*)alloc(256 * 256 * 2);
    u16* wo2T = (u16*)alloc(256 * 2);
    float* sums  = (float*)alloc(3 * 512 * 4);
    float* scsh1 = (float*)alloc(512 * 4);
    float* scsh2 = (float*)alloc(512 * 4);
    float* scsh3 = (float*)alloc(512 * 4);
    float* b2aF  = (float*)alloc(256 * 4);
    u16* S0 = (u16*)alloc((size_t)R1 * 256 * 2);
    u16* S1 = (u16*)alloc((size_t)R1 * 256 * 2);
    u16* S2 = (u16*)alloc((size_t)R1 * 256 * 2);
    u16* BIG1 = (u16*)alloc((size_t)R2 * 256 * 2);
    u16* BIG2 = (u16*)alloc((size_t)R2 * 256 * 2);

    dim3 tgrid(256, 5);
    transpose_all<<<tgrid, 256, 0, stream>>>(w1b, w1bT, w2b, w2bT, w3a, w3aT,
                                             w3b, w3bT, wo1, wo1T);
    zero_stats<<<6, 256, 0, stream>>>(sums, 3 * 512);
    conv_wo2<<<1, 256, 0, stream>>>(wo2, wo2T);

    // mlp1: fc1 (VALU) + fc2 GEMM with fused stats
    mlp1_fc1<<<R1 / 8, 256, 0, stream>>>(x, w1a, b1a, S0);
    gemm_kernel<false, 1, true, 0><<<(R1 / 128) * 2, 256, 0, stream>>>(S0, w1bT, b1b, S1, 256, sums);
    stats_final<<<1, 256, 0, stream>>>(sums, g1, be1, 1.f / R1, scsh1);
    fold_w2a<<<512, 256, 0, stream>>>(w2a, scsh1, w2aT);
    fold_b2a<<<1, 256, 0, stream>>>(w2a, scsh1, b2a, b2aF);

    // mlp2: gather fc1 (BN1 folded, batch-XCD swizzle), fc2 with fused stats
    gemm_kernel<true, 1, false, 1><<<(R2 / 128) * 2, 256, 0, stream>>>(S1, w2aT, b2aF, BIG1, 512, nullptr);
    gemm_kernel<false, 1, true, 0><<<(R2 / 128) * 2, 256, 0, stream>>>(BIG1, w2bT, b2b, BIG2, 256, sums + 512);
    stats_final<<<1, 256, 0, stream>>>(sums + 512, g2, be2, 1.f / R2, scsh2);

    // edge2node (BN2 affine folded in)
    edge2node<<<R1 / 8, 256, 0, stream>>>(BIG2, scsh2, S0);

    // mlp3: two GEMMs, stats fused into fc2
    gemm_kernel<false, 1, false, 0><<<(R1 / 128) * 2, 256, 0, stream>>>(S0, w3aT, b3a, S1, 256, nullptr);
    gemm_kernel<false, 1, true, 0><<<(R1 / 128) * 2, 256, 0, stream>>>(S1, w3bT, b3b, S2, 256, sums + 1024);
    stats_final<<<1, 256, 0, stream>>>(sums + 1024, g3, be3, 1.f / R1, scsh3);

    // head: BN3 affine+relu, wo1 GEMM (relu), dot wo2
    norm_affine_relu<<<(R1 * 32 + 255) / 256, 256, 0, stream>>>(S2, scsh3, S0, R1 * 32);
    gemm_kernel<false, 2, false, 0><<<(R1 / 128) * 2, 256, 0, stream>>>(S0, wo1T, bo1, S1, 256, nullptr);
    head2<<<R1 / 8, 256, 0, stream>>>(S1, wo2T, bo2, out);
}

// Round 7
// 265.173 us; speedup vs baseline: 2.3609x; 1.0627x over previous
//
#include <hip/hip_runtime.h>
#include <hip/hip_bf16.h>
#include <cstdint>

#define DI __device__ __forceinline__

typedef short bf16x8 __attribute__((ext_vector_type(8)));
typedef float f32x4 __attribute__((ext_vector_type(4)));
typedef unsigned short u16;
typedef unsigned short u16x8 __attribute__((ext_vector_type(8)));

static constexpr int NV = 10, NE = 90, TT = 64;
static constexpr int R1 = 20480;   // 32*10*64 node rows
static constexpr int R2 = 184320;  // 32*90*64 edge rows

DI float bf2f(u16 u) { union { unsigned int i; float f; } x; x.i = ((unsigned int)u) << 16; return x.f; }
DI u16 f2bf(float f) { unsigned int u = __float_as_uint(f); return (u16)((u + 0x7FFF + ((u >> 16) & 1)) >> 16); }
DI float elu(float v) { return v > 0.f ? v : __expf(v) - 1.f; }

#define GLL(srcp, dstp) __builtin_amdgcn_global_load_lds( \
    (const __attribute__((address_space(1))) unsigned int*)(srcp), \
    (__attribute__((address_space(3))) unsigned int*)(dstp), 16, 0, 0)

// ---- combined weight transposes: [256,256] f32 -> [256,256] bf16 (n-major) --
__global__ __launch_bounds__(256) void transpose_all(
    const float* __restrict__ s0, u16* __restrict__ d0,
    const float* __restrict__ s1, u16* __restrict__ d1,
    const float* __restrict__ s2, u16* __restrict__ d2,
    const float* __restrict__ s3, u16* __restrict__ d3,
    const float* __restrict__ s4, u16* __restrict__ d4) {
    const float* s; u16* d;
    switch (blockIdx.y) {
        case 0: s = s0; d = d0; break;
        case 1: s = s1; d = d1; break;
        case 2: s = s2; d = d2; break;
        case 3: s = s3; d = d3; break;
        default: s = s4; d = d4; break;
    }
    int idx = blockIdx.x * 256 + threadIdx.x;
    int k = idx >> 8, n = idx & 255;
    d[(size_t)n * 256 + k] = f2bf(s[idx]);
}

__global__ void zero_stats(float* p, int n) {
    int i = blockIdx.x * 256 + threadIdx.x;
    if (i < n) p[i] = 0.f;
}

__global__ void conv_wo2(const float* __restrict__ src, u16* __restrict__ dst) {
    dst[threadIdx.x] = f2bf(src[threadIdx.x]);
}

// fold BN1 affine scale into w2a (transposed), shift into bias
__global__ __launch_bounds__(256) void fold_w2a(const float* __restrict__ w2a,
                                                const float* __restrict__ scsh1,
                                                u16* __restrict__ w2aT) {
    int k = blockIdx.x, n = threadIdx.x;
    w2aT[(size_t)n * 512 + k] = f2bf(scsh1[k & 255] * w2a[k * 256 + n]);
}
// parallel version: one block per output channel n, LDS tree-reduce over k
__global__ __launch_bounds__(256) void fold_b2a(const float* __restrict__ w2a,
                                                const float* __restrict__ scsh1,
                                                const float* __restrict__ b2a,
                                                float* __restrict__ b2aF) {
    __shared__ float red[256];
    int n = blockIdx.x, tid = threadIdx.x;
    float sc = scsh1[256 + tid];
    float s = sc * w2a[tid * 256 + n] + sc * w2a[(tid + 256) * 256 + n];
    red[tid] = s;
    __syncthreads();
    for (int off2 = 128; off2 > 0; off2 >>= 1) {
        if (tid < off2) red[tid] += red[tid + off2];
        __syncthreads();
    }
    if (tid == 0) b2aF[n] = red[0] + b2a[n];
}

__global__ void stats_final(const float* __restrict__ sums, const float* __restrict__ g,
                            const float* __restrict__ be, float invR, float* __restrict__ scsh) {
    int c = threadIdx.x;
    float mu = sums[c] * invR;
    float var = sums[256 + c] * invR - mu * mu;
    float rs = rsqrtf(var + 1e-5f);
    float sc = g[c] * rs;
    scsh[c] = sc;
    scsh[256 + c] = be[c] - mu * sc;
}

// -------------------- mlp1 fc1: K=4, VALU (round-1 verified) -----------------
__global__ __launch_bounds__(256) void mlp1_fc1(const float* __restrict__ x,
                                                const float* __restrict__ w1a,
                                                const float* __restrict__ b1a,
                                                u16* __restrict__ ha) {
    int tid = threadIdx.x;
    int row = blockIdx.x * 8 + (tid >> 5);
    int ch8 = (tid & 31) * 8;
    int b = row / (NV * TT);
    int v = (row >> 6) % NV;
    int t = row & 63;
    const float* xp = x + ((size_t)(b * TT + t) * NV + v) * 4;
    float x0 = xp[0], x1 = xp[1], x2 = xp[2], x3 = xp[3];
    u16x8 pack;
#pragma unroll
    for (int e = 0; e < 8; ++e) {
        int c = ch8 + e;
        float acc = b1a[c] + x0 * w1a[c] + x1 * w1a[256 + c] + x2 * w1a[512 + c] + x3 * w1a[768 + c];
        pack[e] = f2bf(elu(acc));
    }
    *(u16x8*)(ha + (size_t)row * 256 + ch8) = pack;
}

// ============================================================================
// ROUND-6 VERIFIED ENGINE + counted-vmcnt 2-deep pipeline (T4):
//   3 LDS buffers; per K-step:
//     s_waitcnt vmcnt(4)   <- retire MY tile-k GLLs (tile k+1 stays in flight)
//     s_barrier            <- publish: all waves' tile-k LDS writes visible
//     stage(tile k+2)      <- safe: that buffer's readers finished pre-barrier
//     sched_barrier(0)     <- hipcc must not hoist ds_reads above the barrier
//     ds_read(buf k%3) + 16 MFMA
//   Loads of tile k+1/k+2 overlap ~2 full compute sections. Never vmcnt(0)
//   in the main loop (only the final iteration drains).
// SWZ=0: bn-pair shares A-tile on one XCD. SWZ=1: batch -> fixed XCD (gather).
// ============================================================================
template <bool GATHER, int ACT, bool STATS, int SWZ>   // ACT: 1 elu, 2 relu
__global__ __launch_bounds__(256) void gemm_kernel(const u16* __restrict__ A,
                                                   const u16* __restrict__ Wt,
                                                   const float* __restrict__ bias,
                                                   u16* __restrict__ out,
                                                   int K,
                                                   float* __restrict__ stats) {
    __shared__ u16 As[3][128 * 32];
    __shared__ u16 Bs[3][128 * 32];
    const int tid = threadIdx.x;
    const int lane = tid & 63, wid = tid >> 6;

    int bm, bn;
    {
        int bid = blockIdx.x;
        int xcd = bid & 7, slot = bid >> 3;
        if constexpr (SWZ == 1) {
            // 2880 blocks: 32 batches x 45 bm x 2 bn; batch -> fixed XCD
            int batch = xcd + 8 * (slot / 90);
            int j = slot % 90;
            bn = j & 1;
            bm = batch * 45 + (j >> 1);
        } else {
            bn = slot & 1;
            bm = xcd + 8 * (slot >> 1);
        }
    }
    const int m0 = bm * 128, n0 = bn * 128;
    const int wm = wid >> 1, wn = wid & 1;

    const int srow = tid >> 2;           // 0..63 staging row
    const int scol8 = (tid & 3) * 8;     // k-chunk within BK

    size_t abase[2], bbase[2], sb[2], rb[2];
    if constexpr (GATHER) {
#pragma unroll
        for (int p = 0; p < 2; ++p) {
            int m = m0 + srow + p * 64;        // edge row
            int t = m & 63;
            int be = m >> 6;
            int e = be % NE;
            int b = be / NE;
            int s = e / 9;
            int kk = e - s * 9;
            int r = kk + (kk >= s ? 1 : 0);
            sb[p] = ((size_t)((b * NV + s) * TT + t)) * 256;
            rb[p] = ((size_t)((b * NV + r) * TT + t)) * 256;
        }
    } else {
#pragma unroll
        for (int p = 0; p < 2; ++p) abase[p] = (size_t)(m0 + srow + p * 64) * K;
    }
#pragma unroll
    for (int p = 0; p < 2; ++p) bbase[p] = (size_t)(n0 + srow + p * 64) * K;

    f32x4 acc[4][4];
#pragma unroll
    for (int i = 0; i < 4; ++i)
#pragma unroll
        for (int j = 0; j < 4; ++j) acc[i][j] = (f32x4)0.f;

    const int lrow = lane & 15;
    const int lk8 = (lane >> 4) * 8;

    auto stage = [&](int bf, int k0) {
#pragma unroll
        for (int p = 0; p < 2; ++p) {
            const u16* asrc;
            if constexpr (GATHER) {
                int f = k0 + scol8;
                asrc = A + (f < 256 ? sb[p] + f : rb[p] + (f - 256));
            } else {
                asrc = A + abase[p] + k0 + scol8;
            }
            GLL(asrc, &As[bf][(p * 256 + wid * 64) * 8]);
            GLL(Wt + bbase[p] + k0 + scol8, &Bs[bf][(p * 256 + wid * 64) * 8]);
        }
    };

    const int NT = K >> 5;            // 32-wide K tiles (8 or 16)
    stage(0, 0);
    stage(1, 32);
    for (int kt = 0; kt < NT; ++kt) {
        if (kt + 1 < NT) {
            asm volatile("s_waitcnt vmcnt(4)" ::: "memory");   // tile kt retired, kt+1 in flight
        } else {
            asm volatile("s_waitcnt vmcnt(0)" ::: "memory");   // final drain
        }
        __builtin_amdgcn_s_barrier();                           // publish tile kt
        if (kt + 2 < NT) stage((kt + 2) % 3, (kt + 2) * 32);    // 2-deep prefetch
        __builtin_amdgcn_sched_barrier(0);                      // pin ds_reads below barrier
        const int buf = kt % 3;
        bf16x8 a[4], b[4];
#pragma unroll
        for (int i = 0; i < 4; ++i)
            a[i] = *(const bf16x8*)&As[buf][(wm * 64 + i * 16 + lrow) * 32 + lk8];
#pragma unroll
        for (int j = 0; j < 4; ++j)
            b[j] = *(const bf16x8*)&Bs[buf][(wn * 64 + j * 16 + lrow) * 32 + lk8];
#pragma unroll
        for (int i = 0; i < 4; ++i)
#pragma unroll
            for (int j = 0; j < 4; ++j)
                acc[i][j] = __builtin_amdgcn_mfma_f32_16x16x32_bf16(a[i], b[j], acc[i][j], 0, 0, 0);
    }

    // ---- epilogue: bias + act (+fused stats) + store ----
    float bv[4], sv[4], qv[4];
#pragma unroll
    for (int j = 0; j < 4; ++j) {
        bv[j] = bias[n0 + wn * 64 + j * 16 + lrow];
        if constexpr (STATS) { sv[j] = 0.f; qv[j] = 0.f; }
    }
#pragma unroll
    for (int i = 0; i < 4; ++i) {
#pragma unroll
        for (int j = 0; j < 4; ++j) {
            int col = n0 + wn * 64 + j * 16 + lrow;
#pragma unroll
            for (int r = 0; r < 4; ++r) {
                int row = m0 + wm * 64 + i * 16 + (lane >> 4) * 4 + r;
                float v = acc[i][j][r] + bv[j];
                v = (ACT == 1) ? elu(v) : (v > 0.f ? v : 0.f);
                if constexpr (STATS) { sv[j] += v; qv[j] += v * v; }
                out[(size_t)row * 256 + col] = f2bf(v);
            }
        }
    }
    if constexpr (STATS) {
        // col depends only on lrow: reduce over lane bits 4,5
#pragma unroll
        for (int j = 0; j < 4; ++j) {
            float s = sv[j], q_ = qv[j];
            s += __shfl_xor(s, 16); q_ += __shfl_xor(q_, 16);
            s += __shfl_xor(s, 32); q_ += __shfl_xor(q_, 32);
            if ((lane >> 4) == 0) {
                int col = n0 + wn * 64 + j * 16 + lrow;
                atomicAdd(&stats[col], s);
                atomicAdd(&stats[256 + col], q_);
            }
        }
    }
}

// -------------------- elementwise affine + relu (BN3) ------------------------
__global__ __launch_bounds__(256) void norm_affine_relu(const u16* __restrict__ in,
                                                        const float* __restrict__ scsh,
                                                        u16* __restrict__ out, int n8) {
    int i = blockIdx.x * 256 + threadIdx.x;
    if (i >= n8) return;
    size_t base = (size_t)i * 8;
    int ch8 = (int)(base & 255);
    u16x8 v = *(const u16x8*)(in + base);
    u16x8 o;
#pragma unroll
    for (int e = 0; e < 8; ++e) {
        float f = bf2f(v[e]);
        f = scsh[ch8 + e] * f + scsh[256 + ch8 + e];
        o[e] = f2bf(f > 0.f ? f : 0.f);
    }
    *(u16x8*)(out + base) = o;
}

// -------------------- edge2node: incidence sum + BN2 affine (verified) -------
__global__ __launch_bounds__(256) void edge2node(const u16* __restrict__ h2,
                                                 const float* __restrict__ scsh2,
                                                 u16* __restrict__ n1) {
    int tid = threadIdx.x;
    int row = blockIdx.x * 8 + (tid >> 5);
    int ch8 = (tid & 31) * 8;
    int t = row & 63;
    int bv = row >> 6;
    int v = bv % NV;
    int b = bv / NV;
    float acc[8] = {0, 0, 0, 0, 0, 0, 0, 0};
#pragma unroll
    for (int i = 0; i < 9; ++i) {
        int s = i + (i >= v ? 1 : 0);
        int e = s * 9 + (v < s ? v : v - 1);
        u16x8 vv = *(const u16x8*)(h2 + ((size_t)((b * NE + e) * TT + t)) * 256 + ch8);
#pragma unroll
        for (int k = 0; k < 8; ++k) acc[k] += bf2f(vv[k]);
    }
    const float inv9 = 1.f / 9.f;
    u16x8 o;
#pragma unroll
    for (int k = 0; k < 8; ++k) {
        int c = ch8 + k;
        o[k] = f2bf(scsh2[c] * (acc[k] * inv9) + scsh2[256 + c]);
    }
    *(u16x8*)(n1 + (size_t)row * 256 + ch8) = o;
}

// -------------------- final head: dot(a2_row, wo2) + bo2 (verified) ----------
__global__ __launch_bounds__(256) void head2(const u16* __restrict__ a2,
                                             const u16* __restrict__ wo2t,
                                             const float* __restrict__ bo2,
                                             float* __restrict__ out) {
    int tid = threadIdx.x;
    int row = blockIdx.x * 8 + (tid >> 5);
    int l32 = tid & 31;
    int ch8 = l32 * 8;
    u16x8 a = *(const u16x8*)(a2 + (size_t)row * 256 + ch8);
    u16x8 w = *(const u16x8*)(wo2t + ch8);
    float p = 0.f;
#pragma unroll
    for (int k = 0; k < 8; ++k) p += bf2f(a[k]) * bf2f(w[k]);
#pragma unroll
    for (int off = 16; off > 0; off >>= 1) p += __shfl_down(p, off, 32);
    if (l32 == 0) {
        int b = row / (NV * TT);
        int v = (row >> 6) % NV;
        int t = row & 63;
        out[(size_t)(b * TT + t) * NV + v] = p + bo2[0];
    }
}

extern "C" void kernel_launch(void* const* d_in, const int* in_sizes, int n_in,
                              void* d_out, int out_size, void* d_ws, size_t ws_size,
                              hipStream_t stream) {
    const float* x   = (const float*)d_in[0];
    const float* w1a = (const float*)d_in[1];
    const float* b1a = (const float*)d_in[2];
    const float* w1b = (const float*)d_in[3];
    const float* b1b = (const float*)d_in[4];
    const float* g1  = (const float*)d_in[5];
    const float* be1 = (const float*)d_in[6];
    const float* w2a = (const float*)d_in[7];
    const float* b2a = (const float*)d_in[8];
    const float* w2b = (const float*)d_in[9];
    const float* b2b = (const float*)d_in[10];
    const float* g2  = (const float*)d_in[11];
    const float* be2 = (const float*)d_in[12];
    const float* w3a = (const float*)d_in[13];
    const float* b3a = (const float*)d_in[14];
    const float* w3b = (const float*)d_in[15];
    const float* b3b = (const float*)d_in[16];
    const float* g3  = (const float*)d_in[17];
    const float* be3 = (const float*)d_in[18];
    const float* wo1 = (const float*)d_in[19];
    const float* bo1 = (const float*)d_in[20];
    const float* wo2 = (const float*)d_in[21];
    const float* bo2 = (const float*)d_in[22];
    float* out = (float*)d_out;

    char* ws = (char*)d_ws;
    size_t off = 0;
    auto alloc = [&](size_t bytes) {
        void* p = ws + off;
        off = (off + bytes + 255) & ~(size_t)255;
        return p;
    };
    u16* w1bT = (u16*)alloc(256 * 256 * 2);
    u16* w2aT = (u16*)alloc(256 * 512 * 2);
    u16* w2bT = (u16*)alloc(256 * 256 * 2);
    u16* w3aT = (u16*)alloc(256 * 256 * 2);
    u16* w3bT = (u16*)alloc(256 * 256 * 2);
    u16* wo1T = (u16*)alloc(256 * 256 * 2);
    u16* wo2T = (u16*)alloc(256 * 2);
    float* sums  = (float*)alloc(3 * 512 * 4);
    float* scsh1 = (float*)alloc(512 * 4);
    float* scsh2 = (float*)alloc(512 * 4);
    float* scsh3 = (float*)alloc(512 * 4);
    float* b2aF  = (float*)alloc(256 * 4);
    u16* S0 = (u16*)alloc((size_t)R1 * 256 * 2);
    u16* S1 = (u16*)alloc((size_t)R1 * 256 * 2);
    u16* S2 = (u16*)alloc((size_t)R1 * 256 * 2);
    u16* BIG1 = (u16*)alloc((size_t)R2 * 256 * 2);
    u16* BIG2 = (u16*)alloc((size_t)R2 * 256 * 2);

    dim3 tgrid(256, 5);
    transpose_all<<<tgrid, 256, 0, stream>>>(w1b, w1bT, w2b, w2bT, w3a, w3aT,
                                             w3b, w3bT, wo1, wo1T);
    zero_stats<<<6, 256, 0, stream>>>(sums, 3 * 512);
    conv_wo2<<<1, 256, 0, stream>>>(wo2, wo2T);

    // mlp1: fc1 (VALU) + fc2 GEMM with fused stats
    mlp1_fc1<<<R1 / 8, 256, 0, stream>>>(x, w1a, b1a, S0);
    gemm_kernel<false, 1, true, 0><<<(R1 / 128) * 2, 256, 0, stream>>>(S0, w1bT, b1b, S1, 256, sums);
    stats_final<<<1, 256, 0, stream>>>(sums, g1, be1, 1.f / R1, scsh1);
    fold_w2a<<<512, 256, 0, stream>>>(w2a, scsh1, w2aT);
    fold_b2a<<<256, 256, 0, stream>>>(w2a, scsh1, b2a, b2aF);

    // mlp2: gather fc1 (BN1 folded, batch-XCD swizzle), fc2 with fused stats
    gemm_kernel<true, 1, false, 1><<<(R2 / 128) * 2, 256, 0, stream>>>(S1, w2aT, b2aF, BIG1, 512, nullptr);
    gemm_kernel<false, 1, true, 0><<<(R2 / 128) * 2, 256, 0, stream>>>(BIG1, w2bT, b2b, BIG2, 256, sums + 512);
    stats_final<<<1, 256, 0, stream>>>(sums + 512, g2, be2, 1.f / R2, scsh2);

    // edge2node (BN2 affine folded in)
    edge2node<<<R1 / 8, 256, 0, stream>>>(BIG2, scsh2, S0);

    // mlp3: two GEMMs, stats fused into fc2
    gemm_kernel<false, 1, false, 0><<<(R1 / 128) * 2, 256, 0, stream>>>(S0, w3aT, b3a, S1, 256, nullptr);
    gemm_kernel<false, 1, true, 0><<<(R1 / 128) * 2, 256, 0, stream>>>(S1, w3bT, b3b, S2, 256, sums + 1024);
    stats_final<<<1, 256, 0, stream>>>(sums + 1024, g3, be3, 1.f / R1, scsh3);

    // head: BN3 affine+relu, wo1 GEMM (relu), dot wo2
    norm_affine_relu<<<(R1 * 32 + 255) / 256, 256, 0, stream>>>(S2, scsh3, S0, R1 * 32);
    gemm_kernel<false, 2, false, 0><<<(R1 / 128) * 2, 256, 0, stream>>>(S0, wo1T, bo1, S1, 256, nullptr);
    head2<<<R1 / 8, 256, 0, stream>>>(S1, wo2T, bo2, out);
}

// Round 8
// 260.482 us; speedup vs baseline: 2.4034x; 1.0180x over previous
//
#include <hip/hip_runtime.h>
#include <hip/hip_bf16.h>
#include <cstdint>

#define DI __device__ __forceinline__

typedef short bf16x8 __attribute__((ext_vector_type(8)));
typedef float f32x4 __attribute__((ext_vector_type(4)));
typedef unsigned short u16;
typedef unsigned short u16x8 __attribute__((ext_vector_type(8)));

static constexpr int NV = 10, NE = 90, TT = 64;
static constexpr int R1 = 20480;   // 32*10*64 node rows
static constexpr int R2 = 184320;  // 32*90*64 edge rows

DI float bf2f(u16 u) { union { unsigned int i; float f; } x; x.i = ((unsigned int)u) << 16; return x.f; }
DI u16 f2bf(float f) { unsigned int u = __float_as_uint(f); return (u16)((u + 0x7FFF + ((u >> 16) & 1)) >> 16); }
DI float elu(float v) { return v > 0.f ? v : __expf(v) - 1.f; }

#define GLL(srcp, dstp) __builtin_amdgcn_global_load_lds( \
    (const __attribute__((address_space(1))) unsigned int*)(srcp), \
    (__attribute__((address_space(3))) unsigned int*)(dstp), 16, 0, 0)

// ============================================================================
// Weight tile-packing: dst image = EXACTLY the LDS image the GEMM stages.
//   PK[(bn*NT + kt)*2 + p][tid] (u16x8 each) with value
//     w[k = kt*32 + (tid&3)*8 + e][n = bn*128 + p*64 + (tid>>2)]
// so the staging GLL source (base + p*2048 + tid*8) is a contiguous 1KB run
// per wave -> 1 memory transaction instead of 16.
// ============================================================================
// 5 static weights, K=256 (NT=8): blockIdx.x = bn*8+kt, blockIdx.y = which
__global__ __launch_bounds__(256) void pack5(
    const float* __restrict__ s0, u16* __restrict__ d0,
    const float* __restrict__ s1, u16* __restrict__ d1,
    const float* __restrict__ s2, u16* __restrict__ d2,
    const float* __restrict__ s3, u16* __restrict__ d3,
    const float* __restrict__ s4, u16* __restrict__ d4) {
    const float* s; u16* d;
    switch (blockIdx.y) {
        case 0: s = s0; d = d0; break;
        case 1: s = s1; d = d1; break;
        case 2: s = s2; d = d2; break;
        case 3: s = s3; d = d3; break;
        default: s = s4; d = d4; break;
    }
    int tid = threadIdx.x;
    int bn = blockIdx.x >> 3, kt = blockIdx.x & 7;
#pragma unroll
    for (int p = 0; p < 2; ++p) {
        int n = bn * 128 + p * 64 + (tid >> 2);
        int k = kt * 32 + (tid & 3) * 8;
        u16x8 pk;
#pragma unroll
        for (int e = 0; e < 8; ++e) pk[e] = f2bf(s[(size_t)(k + e) * 256 + n]);
        *(u16x8*)(d + ((size_t)((bn * 8 + kt) * 2 + p)) * 2048 + (size_t)tid * 8) = pk;
    }
}

// w2a: K=512 (NT=16), BN1 scale folded in
__global__ __launch_bounds__(256) void pack_w2a(const float* __restrict__ w2a,
                                                const float* __restrict__ scsh1,
                                                u16* __restrict__ d) {
    int tid = threadIdx.x;
    int bn = blockIdx.x >> 4, kt = blockIdx.x & 15;
#pragma unroll
    for (int p = 0; p < 2; ++p) {
        int n = bn * 128 + p * 64 + (tid >> 2);
        int k = kt * 32 + (tid & 3) * 8;
        u16x8 pk;
#pragma unroll
        for (int e = 0; e < 8; ++e)
            pk[e] = f2bf(scsh1[(k + e) & 255] * w2a[(size_t)(k + e) * 256 + n]);
        *(u16x8*)(d + ((size_t)((bn * 16 + kt) * 2 + p)) * 2048 + (size_t)tid * 8) = pk;
    }
}

__global__ void zero_stats(float* p, int n) {
    int i = blockIdx.x * 256 + threadIdx.x;
    if (i < n) p[i] = 0.f;
}

__global__ void conv_wo2(const float* __restrict__ src, u16* __restrict__ dst) {
    dst[threadIdx.x] = f2bf(src[threadIdx.x]);
}

// BN1 shift term folded into fc1 bias: one block per channel n, tree-reduce
__global__ __launch_bounds__(256) void fold_b2a(const float* __restrict__ w2a,
                                                const float* __restrict__ scsh1,
                                                const float* __restrict__ b2a,
                                                float* __restrict__ b2aF) {
    __shared__ float red[256];
    int n = blockIdx.x, tid = threadIdx.x;
    float sc = scsh1[256 + tid];
    float s = sc * w2a[tid * 256 + n] + sc * w2a[(tid + 256) * 256 + n];
    red[tid] = s;
    __syncthreads();
    for (int off2 = 128; off2 > 0; off2 >>= 1) {
        if (tid < off2) red[tid] += red[tid + off2];
        __syncthreads();
    }
    if (tid == 0) b2aF[n] = red[0] + b2a[n];
}

__global__ void stats_final(const float* __restrict__ sums, const float* __restrict__ g,
                            const float* __restrict__ be, float invR, float* __restrict__ scsh) {
    int c = threadIdx.x;
    float mu = sums[c] * invR;
    float var = sums[256 + c] * invR - mu * mu;
    float rs = rsqrtf(var + 1e-5f);
    float sc = g[c] * rs;
    scsh[c] = sc;
    scsh[256 + c] = be[c] - mu * sc;
}

// -------------------- mlp1 fc1: K=4, VALU (round-1 verified) -----------------
__global__ __launch_bounds__(256) void mlp1_fc1(const float* __restrict__ x,
                                                const float* __restrict__ w1a,
                                                const float* __restrict__ b1a,
                                                u16* __restrict__ ha) {
    int tid = threadIdx.x;
    int row = blockIdx.x * 8 + (tid >> 5);
    int ch8 = (tid & 31) * 8;
    int b = row / (NV * TT);
    int v = (row >> 6) % NV;
    int t = row & 63;
    const float* xp = x + ((size_t)(b * TT + t) * NV + v) * 4;
    float x0 = xp[0], x1 = xp[1], x2 = xp[2], x3 = xp[3];
    u16x8 pack;
#pragma unroll
    for (int e = 0; e < 8; ++e) {
        int c = ch8 + e;
        float acc = b1a[c] + x0 * w1a[c] + x1 * w1a[256 + c] + x2 * w1a[512 + c] + x3 * w1a[768 + c];
        pack[e] = f2bf(elu(acc));
    }
    *(u16x8*)(ha + (size_t)row * 256 + ch8) = pack;
}

// ============================================================================
// ROUND-7 ENGINE (3-buf counted-vmcnt pipeline) with PACKED-B staging:
//   B GLL source = PK + (bn*NT+kt)*4096 + p*2048 + tid*8 -> contiguous 1KB
//   per wave-instruction (1 transaction vs 16). LDS image identical to r7,
//   so fragment reads / MFMA / epilogue are byte-identical.
// SWZ=0: bn-pair shares A-tile on one XCD. SWZ=1: batch -> fixed XCD (gather).
// ============================================================================
template <bool GATHER, int ACT, bool STATS, int SWZ>   // ACT: 1 elu, 2 relu
__global__ __launch_bounds__(256) void gemm_kernel(const u16* __restrict__ A,
                                                   const u16* __restrict__ Wt,
                                                   const float* __restrict__ bias,
                                                   u16* __restrict__ out,
                                                   int K,
                                                   float* __restrict__ stats) {
    __shared__ u16 As[3][128 * 32];
    __shared__ u16 Bs[3][128 * 32];
    const int tid = threadIdx.x;
    const int lane = tid & 63, wid = tid >> 6;

    int bm, bn;
    {
        int bid = blockIdx.x;
        int xcd = bid & 7, slot = bid >> 3;
        if constexpr (SWZ == 1) {
            // 2880 blocks: 32 batches x 45 bm x 2 bn; batch -> fixed XCD
            int batch = xcd + 8 * (slot / 90);
            int j = slot % 90;
            bn = j & 1;
            bm = batch * 45 + (j >> 1);
        } else {
            bn = slot & 1;
            bm = xcd + 8 * (slot >> 1);
        }
    }
    const int m0 = bm * 128, n0 = bn * 128;
    const int wm = wid >> 1, wn = wid & 1;

    const int srow = tid >> 2;           // 0..63 staging row
    const int scol8 = (tid & 3) * 8;     // k-chunk within BK

    size_t abase[2], sb[2], rb[2];
    if constexpr (GATHER) {
#pragma unroll
        for (int p = 0; p < 2; ++p) {
            int m = m0 + srow + p * 64;        // edge row
            int t = m & 63;
            int be = m >> 6;
            int e = be % NE;
            int b = be / NE;
            int s = e / 9;
            int kk = e - s * 9;
            int r = kk + (kk >= s ? 1 : 0);
            sb[p] = ((size_t)((b * NV + s) * TT + t)) * 256;
            rb[p] = ((size_t)((b * NV + r) * TT + t)) * 256;
        }
    } else {
#pragma unroll
        for (int p = 0; p < 2; ++p) abase[p] = (size_t)(m0 + srow + p * 64) * K;
    }
    const int NT = K >> 5;                 // number of 32-wide K tiles
    const size_t bnbase = (size_t)bn * NT * 4096;   // packed-B base for this bn

    f32x4 acc[4][4];
#pragma unroll
    for (int i = 0; i < 4; ++i)
#pragma unroll
        for (int j = 0; j < 4; ++j) acc[i][j] = (f32x4)0.f;

    const int lrow = lane & 15;
    const int lk8 = (lane >> 4) * 8;

    auto stage = [&](int bf, int k0) {
        const size_t btile = bnbase + (size_t)(k0 >> 5) * 4096 + (size_t)tid * 8;
#pragma unroll
        for (int p = 0; p < 2; ++p) {
            const u16* asrc;
            if constexpr (GATHER) {
                int f = k0 + scol8;
                asrc = A + (f < 256 ? sb[p] + f : rb[p] + (f - 256));
            } else {
                asrc = A + abase[p] + k0 + scol8;
            }
            GLL(asrc, &As[bf][(p * 256 + wid * 64) * 8]);
            GLL(Wt + btile + p * 2048, &Bs[bf][(p * 256 + wid * 64) * 8]);
        }
    };

    stage(0, 0);
    stage(1, 32);
    for (int kt = 0; kt < NT; ++kt) {
        if (kt + 1 < NT) {
            asm volatile("s_waitcnt vmcnt(4)" ::: "memory");   // tile kt retired, kt+1 in flight
        } else {
            asm volatile("s_waitcnt vmcnt(0)" ::: "memory");   // final drain
        }
        __builtin_amdgcn_s_barrier();                           // publish tile kt
        if (kt + 2 < NT) stage((kt + 2) % 3, (kt + 2) * 32);    // 2-deep prefetch
        __builtin_amdgcn_sched_barrier(0);                      // pin ds_reads below barrier
        const int buf = kt % 3;
        bf16x8 a[4], b[4];
#pragma unroll
        for (int i = 0; i < 4; ++i)
            a[i] = *(const bf16x8*)&As[buf][(wm * 64 + i * 16 + lrow) * 32 + lk8];
#pragma unroll
        for (int j = 0; j < 4; ++j)
            b[j] = *(const bf16x8*)&Bs[buf][(wn * 64 + j * 16 + lrow) * 32 + lk8];
#pragma unroll
        for (int i = 0; i < 4; ++i)
#pragma unroll
            for (int j = 0; j < 4; ++j)
                acc[i][j] = __builtin_amdgcn_mfma_f32_16x16x32_bf16(a[i], b[j], acc[i][j], 0, 0, 0);
    }

    // ---- epilogue: bias + act (+fused stats) + store ----
    float bv[4], sv[4], qv[4];
#pragma unroll
    for (int j = 0; j < 4; ++j) {
        bv[j] = bias[n0 + wn * 64 + j * 16 + lrow];
        if constexpr (STATS) { sv[j] = 0.f; qv[j] = 0.f; }
    }
#pragma unroll
    for (int i = 0; i < 4; ++i) {
#pragma unroll
        for (int j = 0; j < 4; ++j) {
            int col = n0 + wn * 64 + j * 16 + lrow;
#pragma unroll
            for (int r = 0; r < 4; ++r) {
                int row = m0 + wm * 64 + i * 16 + (lane >> 4) * 4 + r;
                float v = acc[i][j][r] + bv[j];
                v = (ACT == 1) ? elu(v) : (v > 0.f ? v : 0.f);
                if constexpr (STATS) { sv[j] += v; qv[j] += v * v; }
                out[(size_t)row * 256 + col] = f2bf(v);
            }
        }
    }
    if constexpr (STATS) {
        // col depends only on lrow: reduce over lane bits 4,5
#pragma unroll
        for (int j = 0; j < 4; ++j) {
            float s = sv[j], q_ = qv[j];
            s += __shfl_xor(s, 16); q_ += __shfl_xor(q_, 16);
            s += __shfl_xor(s, 32); q_ += __shfl_xor(q_, 32);
            if ((lane >> 4) == 0) {
                int col = n0 + wn * 64 + j * 16 + lrow;
                atomicAdd(&stats[col], s);
                atomicAdd(&stats[256 + col], q_);
            }
        }
    }
}

// -------------------- elementwise affine + relu (BN3) ------------------------
__global__ __launch_bounds__(256) void norm_affine_relu(const u16* __restrict__ in,
                                                        const float* __restrict__ scsh,
                                                        u16* __restrict__ out, int n8) {
    int i = blockIdx.x * 256 + threadIdx.x;
    if (i >= n8) return;
    size_t base = (size_t)i * 8;
    int ch8 = (int)(base & 255);
    u16x8 v = *(const u16x8*)(in + base);
    u16x8 o;
#pragma unroll
    for (int e = 0; e < 8; ++e) {
        float f = bf2f(v[e]);
        f = scsh[ch8 + e] * f + scsh[256 + ch8 + e];
        o[e] = f2bf(f > 0.f ? f : 0.f);
    }
    *(u16x8*)(out + base) = o;
}

// -------------------- edge2node: incidence sum + BN2 affine (verified) -------
__global__ __launch_bounds__(256) void edge2node(const u16* __restrict__ h2,
                                                 const float* __restrict__ scsh2,
                                                 u16* __restrict__ n1) {
    int tid = threadIdx.x;
    int row = blockIdx.x * 8 + (tid >> 5);
    int ch8 = (tid & 31) * 8;
    int t = row & 63;
    int bv = row >> 6;
    int v = bv % NV;
    int b = bv / NV;
    float acc[8] = {0, 0, 0, 0, 0, 0, 0, 0};
#pragma unroll
    for (int i = 0; i < 9; ++i) {
        int s = i + (i >= v ? 1 : 0);
        int e = s * 9 + (v < s ? v : v - 1);
        u16x8 vv = *(const u16x8*)(h2 + ((size_t)((b * NE + e) * TT + t)) * 256 + ch8);
#pragma unroll
        for (int k = 0; k < 8; ++k) acc[k] += bf2f(vv[k]);
    }
    const float inv9 = 1.f / 9.f;
    u16x8 o;
#pragma unroll
    for (int k = 0; k < 8; ++k) {
        int c = ch8 + k;
        o[k] = f2bf(scsh2[c] * (acc[k] * inv9) + scsh2[256 + c]);
    }
    *(u16x8*)(n1 + (size_t)row * 256 + ch8) = o;
}

// -------------------- final head: dot(a2_row, wo2) + bo2 (verified) ----------
__global__ __launch_bounds__(256) void head2(const u16* __restrict__ a2,
                                             const u16* __restrict__ wo2t,
                                             const float* __restrict__ bo2,
                                             float* __restrict__ out) {
    int tid = threadIdx.x;
    int row = blockIdx.x * 8 + (tid >> 5);
    int l32 = tid & 31;
    int ch8 = l32 * 8;
    u16x8 a = *(const u16x8*)(a2 + (size_t)row * 256 + ch8);
    u16x8 w = *(const u16x8*)(wo2t + ch8);
    float p = 0.f;
#pragma unroll
    for (int k = 0; k < 8; ++k) p += bf2f(a[k]) * bf2f(w[k]);
#pragma unroll
    for (int off = 16; off > 0; off >>= 1) p += __shfl_down(p, off, 32);
    if (l32 == 0) {
        int b = row / (NV * TT);
        int v = (row >> 6) % NV;
        int t = row & 63;
        out[(size_t)(b * TT + t) * NV + v] = p + bo2[0];
    }
}

extern "C" void kernel_launch(void* const* d_in, const int* in_sizes, int n_in,
                              void* d_out, int out_size, void* d_ws, size_t ws_size,
                              hipStream_t stream) {
    const float* x   = (const float*)d_in[0];
    const float* w1a = (const float*)d_in[1];
    const float* b1a = (const float*)d_in[2];
    const float* w1b = (const float*)d_in[3];
    const float* b1b = (const float*)d_in[4];
    const float* g1  = (const float*)d_in[5];
    const float* be1 = (const float*)d_in[6];
    const float* w2a = (const float*)d_in[7];
    const float* b2a = (const float*)d_in[8];
    const float* w2b = (const float*)d_in[9];
    const float* b2b = (const float*)d_in[10];
    const float* g2  = (const float*)d_in[11];
    const float* be2 = (const float*)d_in[12];
    const float* w3a = (const float*)d_in[13];
    const float* b3a = (const float*)d_in[14];
    const float* w3b = (const float*)d_in[15];
    const float* b3b = (const float*)d_in[16];
    const float* g3  = (const float*)d_in[17];
    const float* be3 = (const float*)d_in[18];
    const float* wo1 = (const float*)d_in[19];
    const float* bo1 = (const float*)d_in[20];
    const float* wo2 = (const float*)d_in[21];
    const float* bo2 = (const float*)d_in[22];
    float* out = (float*)d_out;

    char* ws = (char*)d_ws;
    size_t off = 0;
    auto alloc = [&](size_t bytes) {
        void* p = ws + off;
        off = (off + bytes + 255) & ~(size_t)255;
        return p;
    };
    u16* w1bP = (u16*)alloc(2 * 8 * 4096 * 2);    // tile-packed, K=256
    u16* w2aP = (u16*)alloc(2 * 16 * 4096 * 2);   // tile-packed, K=512 (folded)
    u16* w2bP = (u16*)alloc(2 * 8 * 4096 * 2);
    u16* w3aP = (u16*)alloc(2 * 8 * 4096 * 2);
    u16* w3bP = (u16*)alloc(2 * 8 * 4096 * 2);
    u16* wo1P = (u16*)alloc(2 * 8 * 4096 * 2);
    u16* wo2T = (u16*)alloc(256 * 2);
    float* sums  = (float*)alloc(3 * 512 * 4);
    float* scsh1 = (float*)alloc(512 * 4);
    float* scsh2 = (float*)alloc(512 * 4);
    float* scsh3 = (float*)alloc(512 * 4);
    float* b2aF  = (float*)alloc(256 * 4);
    u16* S0 = (u16*)alloc((size_t)R1 * 256 * 2);
    u16* S1 = (u16*)alloc((size_t)R1 * 256 * 2);
    u16* S2 = (u16*)alloc((size_t)R1 * 256 * 2);
    u16* BIG1 = (u16*)alloc((size_t)R2 * 256 * 2);
    u16* BIG2 = (u16*)alloc((size_t)R2 * 256 * 2);

    dim3 pgrid(16, 5);
    pack5<<<pgrid, 256, 0, stream>>>(w1b, w1bP, w2b, w2bP, w3a, w3aP,
                                     w3b, w3bP, wo1, wo1P);
    zero_stats<<<6, 256, 0, stream>>>(sums, 3 * 512);
    conv_wo2<<<1, 256, 0, stream>>>(wo2, wo2T);

    // mlp1: fc1 (VALU) + fc2 GEMM with fused stats
    mlp1_fc1<<<R1 / 8, 256, 0, stream>>>(x, w1a, b1a, S0);
    gemm_kernel<false, 1, true, 0><<<(R1 / 128) * 2, 256, 0, stream>>>(S0, w1bP, b1b, S1, 256, sums);
    stats_final<<<1, 256, 0, stream>>>(sums, g1, be1, 1.f / R1, scsh1);
    pack_w2a<<<32, 256, 0, stream>>>(w2a, scsh1, w2aP);
    fold_b2a<<<256, 256, 0, stream>>>(w2a, scsh1, b2a, b2aF);

    // mlp2: gather fc1 (BN1 folded, batch-XCD swizzle), fc2 with fused stats
    gemm_kernel<true, 1, false, 1><<<(R2 / 128) * 2, 256, 0, stream>>>(S1, w2aP, b2aF, BIG1, 512, nullptr);
    gemm_kernel<false, 1, true, 0><<<(R2 / 128) * 2, 256, 0, stream>>>(BIG1, w2bP, b2b, BIG2, 256, sums + 512);
    stats_final<<<1, 256, 0, stream>>>(sums + 512, g2, be2, 1.f / R2, scsh2);

    // edge2node (BN2 affine folded in)
    edge2node<<<R1 / 8, 256, 0, stream>>>(BIG2, scsh2, S0);

    // mlp3: two GEMMs, stats fused into fc2
    gemm_kernel<false, 1, false, 0><<<(R1 / 128) * 2, 256, 0, stream>>>(S0, w3aP, b3a, S1, 256, nullptr);
    gemm_kernel<false, 1, true, 0><<<(R1 / 128) * 2, 256, 0, stream>>>(S1, w3bP, b3b, S2, 256, sums + 1024);
    stats_final<<<1, 256, 0, stream>>>(sums + 1024, g3, be3, 1.f / R1, scsh3);

    // head: BN3 affine+relu, wo1 GEMM (relu), dot wo2
    norm_affine_relu<<<(R1 * 32 + 255) / 256, 256, 0, stream>>>(S2, scsh3, S0, R1 * 32);
    gemm_kernel<false, 2, false, 0><<<(R1 / 128) * 2, 256, 0, stream>>>(S0, wo1P, bo1, S1, 256, nullptr);
    head2<<<R1 / 8, 256, 0, stream>>>(S1, wo2T, bo2, out);
}